// Round 1
// baseline (5943.676 us; speedup 1.0000x reference)
//
#include <hip/hip_runtime.h>
#include <cstdint>
#include <cstddef>

#define BN_EPS 1e-5f

// ---------------- helpers ----------------
__device__ __forceinline__ unsigned int ordf(float d) {
  unsigned int u = __float_as_uint(d);
  return (u >> 31) ? ~u : (u | 0x80000000u);
}
__device__ __forceinline__ float unordf(unsigned int u) {
  return __uint_as_float((u >> 31) ? (u & 0x7fffffffu) : ~u);
}
__device__ __forceinline__ unsigned long long shfl_xor_u64(unsigned long long v, int mask) {
  int lo = (int)(unsigned int)v;
  int hi = (int)(unsigned int)(v >> 32);
  lo = __shfl_xor(lo, mask, 64);
  hi = __shfl_xor(hi, mask, 64);
  return (((unsigned long long)(unsigned int)hi) << 32) | (unsigned int)lo;
}

// ---------------- generic fp32 GEMM ----------------
// C[M,N] (ldc) = [ACC? C +] [A or edge-gather] @ W[K,N](ldw) [+ bias] [relu]
// A-mode plain: v = A[r,k]; if bnA: v = bnA[k]*v + bnA[512+k]
// A-mode gather (flags&4): row r -> node i=r>>5, j=gidx[r];
//   k<srcC: src[i,k] ; else src[j,k-srcC]-src[i,k-srcC]
#define GBM 64
#define GBN 64
#define GBK 16

__global__ __launch_bounds__(256)
void mk_gemm(const float* __restrict__ A, const float* __restrict__ src,
             const int* __restrict__ gidx, int srcC,
             const float* __restrict__ bnA,
             const float* __restrict__ W, int ldw,
             const float* __restrict__ bias,
             float* __restrict__ C, int ldc,
             int M, int N, int K, int flags) {
  __shared__ float As[GBK][GBM + 4];
  __shared__ float Ws[GBK][GBN];
  int tid = threadIdx.x;
  int r0 = blockIdx.x * GBM, n0 = blockIdx.y * GBN;
  int ty = tid >> 4, tx = tid & 15;
  float acc[4][4] = {};
  for (int kt = 0; kt < K; kt += GBK) {
#pragma unroll
    for (int it = 0; it < 4; ++it) {
      int l = it * 256 + tid;
      int r = l >> 4, kk = l & 15;
      int gr = r0 + r, gk = kt + kk;
      float v = 0.f;
      if (gk < K && gr < M) {
        if (flags & 4) {
          int i = gr >> 5;
          if (gk < srcC) v = src[(size_t)i * srcC + gk];
          else {
            int j = gidx[gr]; int c = gk - srcC;
            v = src[(size_t)j * srcC + c] - src[(size_t)i * srcC + c];
          }
        } else {
          v = A[(size_t)gr * K + gk];
          if (bnA) v = bnA[gk] * v + bnA[512 + gk];
        }
      }
      As[kk][r] = v;
      int kw = l >> 6, nw = l & 63;
      int gkw = kt + kw;
      Ws[kw][nw] = (gkw < K && (n0 + nw) < N) ? W[(size_t)gkw * ldw + n0 + nw] : 0.f;
    }
    __syncthreads();
#pragma unroll
    for (int kk = 0; kk < GBK; ++kk) {
      float4 a4 = *(const float4*)&As[kk][ty * 4];
      float4 b4 = *(const float4*)&Ws[kk][tx * 4];
      float av[4] = {a4.x, a4.y, a4.z, a4.w};
      float bv[4] = {b4.x, b4.y, b4.z, b4.w};
#pragma unroll
      for (int i = 0; i < 4; ++i)
#pragma unroll
        for (int j = 0; j < 4; ++j)
          acc[i][j] = fmaf(av[i], bv[j], acc[i][j]);
    }
    __syncthreads();
  }
#pragma unroll
  for (int i = 0; i < 4; ++i) {
    int gr = r0 + ty * 4 + i;
    if (gr >= M) continue;
#pragma unroll
    for (int j = 0; j < 4; ++j) {
      int gc = n0 + tx * 4 + j;
      if (gc >= N) continue;
      float v = acc[i][j];
      if (bias) v += bias[gc];
      if (flags & 1) v += C[(size_t)gr * ldc + gc];
      if (flags & 2) v = fmaxf(v, 0.f);
      C[(size_t)gr * ldc + gc] = v;
    }
  }
}

// ---------------- kNN selection ----------------
__device__ __forceinline__ void knn_insert(float* ld, int* li, int& cnt, float d, int j) {
  if (cnt == 32) {
    float wd = ld[31]; int wi = li[31];
    if (d > wd || (d == wd && j > wi)) return;
  }
  int p = (cnt < 32) ? cnt : 31;
  while (p > 0) {
    float pd = ld[p - 1]; int pi = li[p - 1];
    if (pd > d || (pd == d && pi > j)) { ld[p] = pd; li[p] = pi; --p; }
    else break;
  }
  ld[p] = d; li[p] = j;
  if (cnt < 32) ++cnt;
}

__device__ __forceinline__ void knn_merge_write(const float* ld, const int* li, int cnt,
                                                int q, float* st_d, int* st_i, int* idx_only) {
  int p = 0;
  for (int r = 0; r < 32; ++r) {
    unsigned long long key = (p < cnt)
        ? ((((unsigned long long)ordf(ld[p])) << 32) | (unsigned int)li[p])
        : ~0ull;
    unsigned long long m = key;
#pragma unroll
    for (int off = 32; off; off >>= 1) {
      unsigned long long o = shfl_xor_u64(m, off);
      m = (o < m) ? o : m;
    }
    if (key == m) ++p;
    if (threadIdx.x == 0) {
      int j = (int)(unsigned int)(m & 0xffffffffu);
      if (st_i) st_i[q * 32 + r] = j;
      if (st_d) st_d[q * 32 + r] = unordf((unsigned int)(m >> 32));
      if (idx_only) idx_only[q * 32 + r] = j;
    }
  }
}

__global__ __launch_bounds__(64)
void mk_knn_pos(const float* __restrict__ pos, const float* __restrict__ sq,
                int* __restrict__ idxout, int Npts) {
  __shared__ float sd[64 * 33];
  __shared__ int   si[64 * 33];
  int q = blockIdx.x, lane = threadIdx.x;
  float* ld = &sd[lane * 33]; int* li = &si[lane * 33];
  float qx = pos[q * 3], qy = pos[q * 3 + 1], qz = pos[q * 3 + 2], sqq = sq[q];
  int cnt = 0;
  for (int j = lane; j < Npts; j += 64) {
    if (j == q) continue;
    float d = sqq + sq[j] - 2.f * (qx * pos[j * 3] + qy * pos[j * 3 + 1] + qz * pos[j * 3 + 2]);
    knn_insert(ld, li, cnt, d, j);
  }
  knn_merge_write(ld, li, cnt, q, nullptr, nullptr, idxout);
}

__global__ __launch_bounds__(64)
void mk_knn_chunk(const float* __restrict__ S, const float* __restrict__ sq,
                  int c0, int CH, int first,
                  float* __restrict__ st_d, int* __restrict__ st_i, int Npts) {
  __shared__ float sd[64 * 33];
  __shared__ int   si[64 * 33];
  int q = blockIdx.x, lane = threadIdx.x;
  float* ld = &sd[lane * 33]; int* li = &si[lane * 33];
  int cnt = 0;
  if (!first && lane < 32) knn_insert(ld, li, cnt, st_d[q * 32 + lane], st_i[q * 32 + lane]);
  float sqq = sq[q];
  for (int t = lane; t < CH; t += 64) {
    int j = c0 + t;
    if (j == q) continue;
    float d = sqq + sq[j] - 2.f * S[(size_t)q * CH + t];
    knn_insert(ld, li, cnt, d, j);
  }
  knn_merge_write(ld, li, cnt, q, st_d, st_i, nullptr);
}

// ---------------- small utility kernels ----------------
__global__ void mk_sqnorm(const float* __restrict__ x, float* __restrict__ sq, int Npts, int Cdim) {
  int i = blockIdx.x * blockDim.x + threadIdx.x;
  if (i >= Npts) return;
  float s = 0.f;
  for (int c = 0; c < Cdim; ++c) { float v = x[(size_t)i * Cdim + c]; s = fmaf(v, v, s); }
  sq[i] = s;
}

__global__ void mk_transpose(const float* __restrict__ x, float* __restrict__ xT, int Npts, int Cdim) {
  int g = blockIdx.x * blockDim.x + threadIdx.x;
  if (g >= Npts * Cdim) return;
  int i = g / Cdim, c = g % Cdim;
  xT[(size_t)c * Npts + i] = x[g];
}

__global__ __launch_bounds__(256)
void mk_stats(const float* __restrict__ h, float* __restrict__ stats, int M, int Cdim, int RPB) {
  __shared__ float ssum[512], ssq[512];
  for (int c = threadIdx.x; c < Cdim; c += 256) { ssum[c] = 0.f; ssq[c] = 0.f; }
  __syncthreads();
  int G = Cdim >> 2;
  int c4 = (threadIdx.x % G) * 4;
  int rsub = threadIdx.x / G;
  int step = 256 / G;
  int r0 = blockIdx.x * RPB;
  int r1 = r0 + RPB; if (r1 > M) r1 = M;
  float s0 = 0, s1 = 0, s2 = 0, s3 = 0, q0 = 0, q1 = 0, q2 = 0, q3 = 0;
  for (int r = r0 + rsub; r < r1; r += step) {
    float4 v = *(const float4*)&h[(size_t)r * Cdim + c4];
    s0 += v.x; s1 += v.y; s2 += v.z; s3 += v.w;
    q0 = fmaf(v.x, v.x, q0); q1 = fmaf(v.y, v.y, q1);
    q2 = fmaf(v.z, v.z, q2); q3 = fmaf(v.w, v.w, q3);
  }
  atomicAdd(&ssum[c4 + 0], s0); atomicAdd(&ssum[c4 + 1], s1);
  atomicAdd(&ssum[c4 + 2], s2); atomicAdd(&ssum[c4 + 3], s3);
  atomicAdd(&ssq[c4 + 0], q0); atomicAdd(&ssq[c4 + 1], q1);
  atomicAdd(&ssq[c4 + 2], q2); atomicAdd(&ssq[c4 + 3], q3);
  __syncthreads();
  for (int c = threadIdx.x; c < Cdim; c += 256) {
    atomicAdd(&stats[c], ssum[c]);
    atomicAdd(&stats[512 + c], ssq[c]);
  }
}

__global__ void mk_bnfin(const float* __restrict__ stats, const float* __restrict__ g,
                         const float* __restrict__ beta, float* __restrict__ bn,
                         float Minv, int Cdim) {
  int c = blockIdx.x * blockDim.x + threadIdx.x;
  if (c >= Cdim) return;
  float mu = stats[c] * Minv;
  float var = stats[512 + c] * Minv - mu * mu;
  float a = g[c] * rsqrtf(var + BN_EPS);
  bn[c] = a;
  bn[512 + c] = beta[c] - a * mu;
}

__global__ void mk_maxpool(const float* __restrict__ h, const float* __restrict__ bn,
                           float* __restrict__ xo, int Npts, int Cdim) {
  int gid = blockIdx.x * blockDim.x + threadIdx.x;
  if (gid >= Npts * Cdim) return;
  int i = gid / Cdim, c = gid % Cdim;
  float a = bn[c], b = bn[512 + c];
  float m = -1e30f;
  const float* p = &h[(size_t)i * 32 * Cdim + c];
  for (int j = 0; j < 32; ++j) m = fmaxf(m, fmaf(a, p[(size_t)j * Cdim], b));
  xo[gid] = m;
}

__global__ void mk_deg(const int* __restrict__ col, float* __restrict__ deg, int E) {
  int e = blockIdx.x * blockDim.x + threadIdx.x;
  if (e < E) atomicAdd(&deg[col[e]], 1.f);
}
__global__ void mk_dinv(float* __restrict__ deg, int Npts) {
  int i = blockIdx.x * blockDim.x + threadIdx.x;
  if (i >= Npts) return;
  float d = deg[i];
  deg[i] = (d > 0.f) ? rsqrtf(fmaxf(d, 1.f)) : 0.f;
}
__global__ void mk_norm(const int* __restrict__ row, const int* __restrict__ col,
                        const float* __restrict__ dinv, float* __restrict__ nrm, int E) {
  int e = blockIdx.x * blockDim.x + threadIdx.x;
  if (e < E) nrm[e] = dinv[row[e]] * dinv[col[e]];
}
__global__ void mk_prop(const float* __restrict__ h, const int* __restrict__ row,
                        const int* __restrict__ col, const float* __restrict__ nrm,
                        float* __restrict__ out, int E, int Cdim) {
  int G = Cdim >> 2;
  int gid = blockIdx.x * blockDim.x + threadIdx.x;
  if (gid >= E * G) return;
  int e = gid / G, c4 = (gid % G) * 4;
  float w = nrm[e];
  int r = row[e], cl = col[e];
  float4 v = *(const float4*)&h[(size_t)r * Cdim + c4];
  float* o = &out[(size_t)cl * Cdim + c4];
  atomicAdd(&o[0], w * v.x); atomicAdd(&o[1], w * v.y);
  atomicAdd(&o[2], w * v.z); atomicAdd(&o[3], w * v.w);
}

__global__ __launch_bounds__(256)
void mk_gemv_out(const float* __restrict__ h, const float* __restrict__ bn,
                 const float* __restrict__ w, const float* __restrict__ b,
                 float* __restrict__ out, int Npts) {
  int row = blockIdx.x * 4 + (threadIdx.x >> 6);
  int lane = threadIdx.x & 63;
  if (row >= Npts) return;
  int c = lane * 4;
  float4 v = *(const float4*)&h[(size_t)row * 256 + c];
  float s = (bn[c] * v.x + bn[512 + c]) * w[c]
          + (bn[c + 1] * v.y + bn[512 + c + 1]) * w[c + 1]
          + (bn[c + 2] * v.z + bn[512 + c + 2]) * w[c + 2]
          + (bn[c + 3] * v.w + bn[512 + c + 3]) * w[c + 3];
#pragma unroll
  for (int off = 32; off; off >>= 1) s += __shfl_xor(s, off, 64);
  if (lane == 0) out[row] = s + b[0];
}

// ---------------- host ----------------
extern "C" void kernel_launch(void* const* d_in, const int* in_sizes, int n_in,
                              void* d_out, int out_size, void* d_ws, size_t ws_size,
                              hipStream_t stream) {
  const int N = 8192;
  const int NE = N * 32;  // 262144 edge messages
  const float* pos = (const float*)d_in[0];
  const float* xin = (const float*)d_in[1];
  const int* ei = (const int*)d_in[2];
  const int E = in_sizes[2] / 2;
  const int* erow = ei;
  const int* ecol = ei + E;
  const float* mlp1_W1  = (const float*)d_in[3];
  const float* mlp1_W23 = (const float*)d_in[4];
  const float* mlp1_b   = (const float*)d_in[5];
  const float* mlp1_g   = (const float*)d_in[6];
  const float* mlp1_be  = (const float*)d_in[7];
  const float* mlp2_W   = (const float*)d_in[8];
  const float* mlp2_b   = (const float*)d_in[9];
  const float* mlp2_g   = (const float*)d_in[10];
  const float* mlp2_be  = (const float*)d_in[11];
  const float* lin1_W   = (const float*)d_in[12];
  const float* lin1_b   = (const float*)d_in[13];
  const float* lin1_g   = (const float*)d_in[14];
  const float* lin1_be  = (const float*)d_in[15];
  const float* tag1_W   = (const float*)d_in[16];
  const float* tag1_b   = (const float*)d_in[17];
  const float* tag2_W   = (const float*)d_in[18];
  const float* tag2_b   = (const float*)d_in[19];
  const float* lin2_W   = (const float*)d_in[20];
  const float* lin2_b   = (const float*)d_in[21];
  const float* lin2_g   = (const float*)d_in[22];
  const float* lin2_be  = (const float*)d_in[23];
  const float* mix1_W   = (const float*)d_in[24];
  const float* mix1_b   = (const float*)d_in[25];
  const float* mix1_g   = (const float*)d_in[26];
  const float* mix1_be  = (const float*)d_in[27];
  const float* mix2_W   = (const float*)d_in[28];
  const float* mix2_b   = (const float*)d_in[29];
  const float* mix2_g   = (const float*)d_in[30];
  const float* mix2_be  = (const float*)d_in[31];
  const float* outW     = (const float*)d_in[32];
  const float* outB     = (const float*)d_in[33];

  char* base = (char*)d_ws;
  size_t off = 0;
  auto alloc = [&](size_t b) -> void* {
    void* p = base + off;
    off += (b + 255) & ~(size_t)255;
    return p;
  };
  // 128 MB phase-shared slab
  float* BIG = (float*)alloc(134217728ull);
  float* hA = BIG;                  // mlp1 ping (64 MB)
  float* hB = BIG + 16777216;       // mlp1 pong (64 MB)
  float* Sb = BIG;                  // knn2 S chunk (64 MB)
  float* hC = BIG;                  // mlp2 h (128 MB)
  float* out_dg = BIG;              // [8192,512] 16 MB (after mlp2 done)
  float* out_g  = BIG + 4194304;
  float* mh1    = BIG + 8388608;
  float* mh2    = BIG + 12582912;
  int*   idx1 = (int*)alloc((size_t)NE * 4);
  float* st_d = (float*)alloc((size_t)NE * 4);
  int*   st_i = (int*)alloc((size_t)NE * 4);
  float* x1  = (float*)alloc((size_t)N * 64 * 4);
  float* x2  = (float*)alloc((size_t)N * 128 * 4);
  float* g1  = (float*)alloc((size_t)N * 64 * 4);
  float* g2  = (float*)alloc((size_t)N * 128 * 4);
  float* x1T = (float*)alloc((size_t)N * 64 * 4);
  float* sqp = (float*)alloc((size_t)N * 4);
  float* sqx = (float*)alloc((size_t)N * 4);
  float* dinv = (float*)alloc((size_t)N * 4);
  float* enorm = (float*)alloc((size_t)E * 4);
  float* tpa = (float*)alloc((size_t)N * 64 * 4);
  float* tpb = (float*)alloc((size_t)N * 64 * 4);
  float* stats = (float*)alloc(1024 * 4);
  float* bnb = (float*)alloc(8 * 1024 * 4);
  auto bn = [&](int i) { return bnb + (size_t)i * 1024; };

  auto gemm = [&](const float* A, const float* src, const int* gidx, int srcC,
                  const float* bnA, const float* W, int ldw, const float* bias,
                  float* Cp, int ldc, int M, int Nn, int Kk, int flags) {
    dim3 g(M / 64, (Nn + 63) / 64);
    mk_gemm<<<g, 256, 0, stream>>>(A, src, gidx, srcC, bnA, W, ldw, bias, Cp, ldc, M, Nn, Kk, flags);
  };
  auto statsbn = [&](const float* h, int M, int C, const float* gg, const float* bb, float* bno) {
    hipMemsetAsync(stats, 0, 4096, stream);
    int RPB = (M + 127) / 128;
    mk_stats<<<128, 256, 0, stream>>>(h, stats, M, C, RPB);
    mk_bnfin<<<(C + 255) / 256, 256, 0, stream>>>(stats, gg, bb, bno, 1.f / M, C);
  };

  // ---- kNN-1 on pos ----
  mk_sqnorm<<<32, 256, 0, stream>>>(pos, sqp, N, 3);
  mk_knn_pos<<<N, 64, 0, stream>>>(pos, sqp, idx1, N);

  // ---- edge MLP1 (6->64->64->64, BN batch stats over 262144 rows) ----
  gemm(nullptr, pos, idx1, 3, nullptr, mlp1_W1, 64, mlp1_b, hA, 64, NE, 64, 6, 4 | 2);
  statsbn(hA, NE, 64, mlp1_g, mlp1_be, bn(0));
  gemm(hA, nullptr, nullptr, 0, bn(0), mlp1_W23, 64, mlp1_b + 64, hB, 64, NE, 64, 64, 2);
  statsbn(hB, NE, 64, mlp1_g + 64, mlp1_be + 64, bn(1));
  gemm(hB, nullptr, nullptr, 0, bn(1), mlp1_W23 + 4096, 64, mlp1_b + 128, hA, 64, NE, 64, 64, 2);
  statsbn(hA, NE, 64, mlp1_g + 128, mlp1_be + 128, bn(2));
  mk_maxpool<<<(N * 64) / 256, 256, 0, stream>>>(hA, bn(2), x1, N, 64);

  // ---- kNN-2 on x1 (chunked S = x1 @ x1^T) ----
  mk_sqnorm<<<32, 256, 0, stream>>>(x1, sqx, N, 64);
  mk_transpose<<<(N * 64) / 256, 256, 0, stream>>>(x1, x1T, N, 64);
  for (int c = 0; c < 4; ++c) {
    gemm(x1, nullptr, nullptr, 0, nullptr, x1T + c * 2048, N, nullptr, Sb, 2048, N, 2048, 64, 0);
    mk_knn_chunk<<<N, 64, 0, stream>>>(Sb, sqx, c * 2048, 2048, c == 0 ? 1 : 0, st_d, st_i, N);
  }

  // ---- edge MLP2 (128->128) ----
  gemm(nullptr, x1, st_i, 64, nullptr, mlp2_W, 128, mlp2_b, hC, 128, NE, 128, 128, 4 | 2);
  statsbn(hC, NE, 128, mlp2_g, mlp2_be, bn(3));
  mk_maxpool<<<(N * 128) / 256, 256, 0, stream>>>(hC, bn(3), x2, N, 128);

  // ---- lin1: [x1,x2] -> 512 ----
  gemm(x1, nullptr, nullptr, 0, nullptr, lin1_W, 512, nullptr, out_dg, 512, N, 512, 64, 0);
  gemm(x2, nullptr, nullptr, 0, nullptr, lin1_W + 64 * 512, 512, lin1_b, out_dg, 512, N, 512, 128, 1 | 2);
  statsbn(out_dg, N, 512, lin1_g, lin1_be, bn(4));

  // ---- TAG branch ----
  hipMemsetAsync(dinv, 0, (size_t)N * 4, stream);
  mk_deg<<<(E + 255) / 256, 256, 0, stream>>>(ecol, dinv, E);
  mk_dinv<<<32, 256, 0, stream>>>(dinv, N);
  mk_norm<<<(E + 255) / 256, 256, 0, stream>>>(erow, ecol, dinv, enorm, E);
  // tag1 (C=4 -> 64)
  gemm(xin, nullptr, nullptr, 0, nullptr, tag1_W, 64, tag1_b, g1, 64, N, 64, 4, 0);
  hipMemsetAsync(tpb, 0, (size_t)N * 4 * 4, stream);
  mk_prop<<<(E + 255) / 256, 256, 0, stream>>>(xin, erow, ecol, enorm, tpb, E, 4);
  gemm(tpb, nullptr, nullptr, 0, nullptr, tag1_W + 256, 64, nullptr, g1, 64, N, 64, 4, 1);
  hipMemsetAsync(tpa, 0, (size_t)N * 4 * 4, stream);
  mk_prop<<<(E + 255) / 256, 256, 0, stream>>>(tpb, erow, ecol, enorm, tpa, E, 4);
  gemm(tpa, nullptr, nullptr, 0, nullptr, tag1_W + 512, 64, nullptr, g1, 64, N, 64, 4, 1);
  hipMemsetAsync(tpb, 0, (size_t)N * 4 * 4, stream);
  mk_prop<<<(E + 255) / 256, 256, 0, stream>>>(tpa, erow, ecol, enorm, tpb, E, 4);
  gemm(tpb, nullptr, nullptr, 0, nullptr, tag1_W + 768, 64, nullptr, g1, 64, N, 64, 4, 1 | 2);
  // tag2 (C=64 -> 128)
  gemm(g1, nullptr, nullptr, 0, nullptr, tag2_W, 128, tag2_b, g2, 128, N, 128, 64, 0);
  hipMemsetAsync(tpa, 0, (size_t)N * 64 * 4, stream);
  mk_prop<<<(E * 16 + 255) / 256, 256, 0, stream>>>(g1, erow, ecol, enorm, tpa, E, 64);
  gemm(tpa, nullptr, nullptr, 0, nullptr, tag2_W + 8192, 128, nullptr, g2, 128, N, 128, 64, 1);
  hipMemsetAsync(tpb, 0, (size_t)N * 64 * 4, stream);
  mk_prop<<<(E * 16 + 255) / 256, 256, 0, stream>>>(tpa, erow, ecol, enorm, tpb, E, 64);
  gemm(tpb, nullptr, nullptr, 0, nullptr, tag2_W + 16384, 128, nullptr, g2, 128, N, 128, 64, 1);
  hipMemsetAsync(tpa, 0, (size_t)N * 64 * 4, stream);
  mk_prop<<<(E * 16 + 255) / 256, 256, 0, stream>>>(tpb, erow, ecol, enorm, tpa, E, 64);
  gemm(tpa, nullptr, nullptr, 0, nullptr, tag2_W + 24576, 128, nullptr, g2, 128, N, 128, 64, 1 | 2);
  // lin2
  gemm(g1, nullptr, nullptr, 0, nullptr, lin2_W, 512, nullptr, out_g, 512, N, 512, 64, 0);
  gemm(g2, nullptr, nullptr, 0, nullptr, lin2_W + 64 * 512, 512, lin2_b, out_g, 512, N, 512, 128, 1 | 2);
  statsbn(out_g, N, 512, lin2_g, lin2_be, bn(5));

  // ---- mix head ----
  gemm(out_dg, nullptr, nullptr, 0, bn(4), mix1_W, 512, nullptr, mh1, 512, N, 512, 512, 0);
  gemm(out_g, nullptr, nullptr, 0, bn(5), mix1_W + 512 * 512, 512, mix1_b, mh1, 512, N, 512, 512, 1 | 2);
  statsbn(mh1, N, 512, mix1_g, mix1_be, bn(6));
  gemm(mh1, nullptr, nullptr, 0, bn(6), mix2_W, 256, mix2_b, mh2, 256, N, 256, 512, 2);
  statsbn(mh2, N, 256, mix2_g, mix2_be, bn(7));
  mk_gemv_out<<<N / 4, 256, 0, stream>>>(mh2, bn(7), outW, outB, (float*)d_out, N);
}

// Round 2
// 3273.032 us; speedup vs baseline: 1.8160x; 1.8160x over previous
//
#include <hip/hip_runtime.h>
#include <cstdint>
#include <cstddef>

#define BN_EPS 1e-5f
#define NBIN 4096
#define MAXB 512

// ---------------- helpers ----------------
__device__ __forceinline__ unsigned int ordf(float d) {
  unsigned int u = __float_as_uint(d);
  return (u >> 31) ? ~u : (u | 0x80000000u);
}

struct SelCtl {
  unsigned int B1, cum1, B2, cum2, acc, bnd;
};

// threads 0..63 call this; finds first bin B with cum(B) >= target.
// outCum = count strictly before bin B.
__device__ __forceinline__ void find_bin(const unsigned int* hist, unsigned int target,
                                         unsigned int* outB, unsigned int* outCum) {
  int lane = threadIdx.x;
  unsigned int run = 0;
  for (int c = 0; c < NBIN / 64; ++c) {
    unsigned int v = hist[c * 64 + lane];
    unsigned int s = v;
#pragma unroll
    for (int off = 1; off < 64; off <<= 1) {
      unsigned int t = __shfl_up(s, off, 64);
      if (lane >= off) s += t;
    }
    unsigned int tot = __shfl(s, 63, 64);
    if (run + tot >= target) {
      unsigned long long mask = __ballot((run + s) >= target);
      int first = __ffsll((unsigned long long)mask) - 1;
      unsigned int vf = __shfl(v, first, 64);
      unsigned int sf = __shfl(s, first, 64);
      if (lane == 0) { *outB = (unsigned)(c * 64 + first); *outCum = run + sf - vf; }
      return;
    }
    run += tot;
  }
  if (lane == 0) { *outB = NBIN - 1; *outCum = run; }
}

// L1 key = k>>20 (top 12 bits, monotone incl sign), L2 = (k>>8)&0xFFF.
template <typename IdxF, typename EmitF>
__device__ __forceinline__ void select32(const unsigned int* skey, int ncand,
                                         unsigned int* hist, unsigned long long* bbuf,
                                         SelCtl* ctl, IdxF idxOf, EmitF emit) {
  int tid = threadIdx.x;
  for (int b = tid; b < NBIN; b += 256) hist[b] = 0;
  if (tid == 0) { ctl->acc = 0; ctl->bnd = 0; }
  __syncthreads();
  for (int c = tid; c < ncand; c += 256) atomicAdd(&hist[skey[c] >> 20], 1u);
  __syncthreads();
  if (tid < 64) find_bin(hist, 32u, &ctl->B1, &ctl->cum1);
  __syncthreads();
  unsigned int B1 = ctl->B1, cum1 = ctl->cum1;
  for (int b = tid; b < NBIN; b += 256) hist[b] = 0;
  __syncthreads();
  for (int c = tid; c < ncand; c += 256) {
    unsigned int k = skey[c];
    if ((k >> 20) == B1) atomicAdd(&hist[(k >> 8) & 0xFFFu], 1u);
  }
  __syncthreads();
  if (tid < 64) find_bin(hist, 32u - cum1, &ctl->B2, &ctl->cum2);
  __syncthreads();
  unsigned int B2 = ctl->B2;
  for (int c = tid; c < ncand; c += 256) {
    unsigned int k = skey[c];
    unsigned int l1 = k >> 20;
    if (l1 > B1) continue;
    unsigned int l2 = (k >> 8) & 0xFFFu;
    if (l1 < B1 || l2 < B2) {
      unsigned int s = atomicAdd(&ctl->acc, 1u);
      emit((int)s, idxOf(c), k);
    } else if (l2 == B2) {
      unsigned int s = atomicAdd(&ctl->bnd, 1u);
      if (s < MAXB) bbuf[s] = (((unsigned long long)k) << 32) | (unsigned int)idxOf(c);
    }
  }
  __syncthreads();
  int acc = (int)ctl->acc;          // == cum1 + cum2, always < 32
  int need = 32 - acc;
  int m = (int)ctl->bnd; if (m > MAXB) m = MAXB;
  for (int e = tid; e < m; e += 256) {
    unsigned long long me = bbuf[e];
    int rank = 0;
    for (int f = 0; f < m; ++f) rank += (bbuf[f] < me) ? 1 : 0;
    if (rank < need) emit(acc + rank, (int)(unsigned int)(me & 0xffffffffu), (unsigned int)(me >> 32));
  }
}

__global__ __launch_bounds__(256)
void mk_knn1(const float* __restrict__ pos, const float* __restrict__ sq,
             int* __restrict__ idxout, int Npts) {
  __shared__ unsigned int skey[8192];
  __shared__ unsigned int hist[NBIN];
  __shared__ unsigned long long bbuf[MAXB];
  __shared__ SelCtl ctl;
  int q = blockIdx.x, tid = threadIdx.x;
  float qx = pos[q * 3], qy = pos[q * 3 + 1], qz = pos[q * 3 + 2], sqq = sq[q];
  for (int j = tid; j < Npts; j += 256) {
    float d = sqq + sq[j] - 2.f * (qx * pos[j * 3] + qy * pos[j * 3 + 1] + qz * pos[j * 3 + 2]);
    skey[j] = (j == q) ? 0xFFFFFFFFu : ordf(d);
  }
  __syncthreads();
  select32(skey, Npts, hist, bbuf, &ctl,
           [](int c) { return c; },
           [&](int s, int j, unsigned int) { idxout[q * 32 + s] = j; });
}

__global__ __launch_bounds__(256)
void mk_knn2(const float* __restrict__ S, const float* __restrict__ sq,
             int c0, int CH, int first,
             unsigned int* __restrict__ st_k, int* __restrict__ st_i, int Npts) {
  __shared__ unsigned int skey[2048 + 32];
  __shared__ int cidx[32];
  __shared__ unsigned int hist[NBIN];
  __shared__ unsigned long long bbuf[MAXB];
  __shared__ SelCtl ctl;
  int q = blockIdx.x, tid = threadIdx.x;
  float sqq = sq[q];
  for (int t = tid; t < CH; t += 256) {
    int j = c0 + t;
    float d = sqq + sq[j] - 2.f * S[(size_t)q * CH + t];
    skey[t] = (j == q) ? 0xFFFFFFFFu : ordf(d);
  }
  if (tid < 32) {
    if (first) { skey[CH + tid] = 0xFFFFFFFFu; cidx[tid] = 0; }
    else       { skey[CH + tid] = st_k[q * 32 + tid]; cidx[tid] = st_i[q * 32 + tid]; }
  }
  __syncthreads();
  select32(skey, CH + 32, hist, bbuf, &ctl,
           [&](int c) { return (c < CH) ? (c0 + c) : cidx[c - CH]; },
           [&](int s, int j, unsigned int k) { st_k[q * 32 + s] = k; st_i[q * 32 + s] = j; });
}

// ---------------- generic fp32 GEMM ----------------
// C[M,N] (ldc) = [ACC? C +] [A or edge-gather] @ W[K,N](ldw) [+ bias] [relu]
// A-mode plain: v = A[r,k]; if bnA: v = bnA[k]*v + bnA[512+k]
// A-mode gather (flags&4): row r -> node i=r>>5, j=gidx[r];
//   k<srcC: src[i,k] ; else src[j,k-srcC]-src[i,k-srcC]
#define GBM 64
#define GBN 64
#define GBK 16

__global__ __launch_bounds__(256)
void mk_gemm(const float* __restrict__ A, const float* __restrict__ src,
             const int* __restrict__ gidx, int srcC,
             const float* __restrict__ bnA,
             const float* __restrict__ W, int ldw,
             const float* __restrict__ bias,
             float* __restrict__ C, int ldc,
             int M, int N, int K, int flags) {
  __shared__ float As[GBK][GBM + 4];
  __shared__ float Ws[GBK][GBN];
  int tid = threadIdx.x;
  int r0 = blockIdx.x * GBM, n0 = blockIdx.y * GBN;
  int ty = tid >> 4, tx = tid & 15;
  float acc[4][4] = {};
  for (int kt = 0; kt < K; kt += GBK) {
#pragma unroll
    for (int it = 0; it < 4; ++it) {
      int l = it * 256 + tid;
      int r = l >> 4, kk = l & 15;
      int gr = r0 + r, gk = kt + kk;
      float v = 0.f;
      if (gk < K && gr < M) {
        if (flags & 4) {
          int i = gr >> 5;
          if (gk < srcC) v = src[(size_t)i * srcC + gk];
          else {
            int j = gidx[gr]; int c = gk - srcC;
            v = src[(size_t)j * srcC + c] - src[(size_t)i * srcC + c];
          }
        } else {
          v = A[(size_t)gr * K + gk];
          if (bnA) v = bnA[gk] * v + bnA[512 + gk];
        }
      }
      As[kk][r] = v;
      int kw = l >> 6, nw = l & 63;
      int gkw = kt + kw;
      Ws[kw][nw] = (gkw < K && (n0 + nw) < N) ? W[(size_t)gkw * ldw + n0 + nw] : 0.f;
    }
    __syncthreads();
#pragma unroll
    for (int kk = 0; kk < GBK; ++kk) {
      float4 a4 = *(const float4*)&As[kk][ty * 4];
      float4 b4 = *(const float4*)&Ws[kk][tx * 4];
      float av[4] = {a4.x, a4.y, a4.z, a4.w};
      float bv[4] = {b4.x, b4.y, b4.z, b4.w};
#pragma unroll
      for (int i = 0; i < 4; ++i)
#pragma unroll
        for (int j = 0; j < 4; ++j)
          acc[i][j] = fmaf(av[i], bv[j], acc[i][j]);
    }
    __syncthreads();
  }
#pragma unroll
  for (int i = 0; i < 4; ++i) {
    int gr = r0 + ty * 4 + i;
    if (gr >= M) continue;
#pragma unroll
    for (int j = 0; j < 4; ++j) {
      int gc = n0 + tx * 4 + j;
      if (gc >= N) continue;
      float v = acc[i][j];
      if (bias) v += bias[gc];
      if (flags & 1) v += C[(size_t)gr * ldc + gc];
      if (flags & 2) v = fmaxf(v, 0.f);
      C[(size_t)gr * ldc + gc] = v;
    }
  }
}

// ---------------- small utility kernels ----------------
__global__ void mk_sqnorm(const float* __restrict__ x, float* __restrict__ sq, int Npts, int Cdim) {
  int i = blockIdx.x * blockDim.x + threadIdx.x;
  if (i >= Npts) return;
  float s = 0.f;
  for (int c = 0; c < Cdim; ++c) { float v = x[(size_t)i * Cdim + c]; s = fmaf(v, v, s); }
  sq[i] = s;
}

__global__ void mk_transpose(const float* __restrict__ x, float* __restrict__ xT, int Npts, int Cdim) {
  int g = blockIdx.x * blockDim.x + threadIdx.x;
  if (g >= Npts * Cdim) return;
  int i = g / Cdim, c = g % Cdim;
  xT[(size_t)c * Npts + i] = x[g];
}

__global__ __launch_bounds__(256)
void mk_stats(const float* __restrict__ h, float* __restrict__ stats, int M, int Cdim, int RPB) {
  __shared__ float ssum[512], ssq[512];
  for (int c = threadIdx.x; c < Cdim; c += 256) { ssum[c] = 0.f; ssq[c] = 0.f; }
  __syncthreads();
  int G = Cdim >> 2;
  int c4 = (threadIdx.x % G) * 4;
  int rsub = threadIdx.x / G;
  int step = 256 / G;
  int r0 = blockIdx.x * RPB;
  int r1 = r0 + RPB; if (r1 > M) r1 = M;
  float s0 = 0, s1 = 0, s2 = 0, s3 = 0, q0 = 0, q1 = 0, q2 = 0, q3 = 0;
  for (int r = r0 + rsub; r < r1; r += step) {
    float4 v = *(const float4*)&h[(size_t)r * Cdim + c4];
    s0 += v.x; s1 += v.y; s2 += v.z; s3 += v.w;
    q0 = fmaf(v.x, v.x, q0); q1 = fmaf(v.y, v.y, q1);
    q2 = fmaf(v.z, v.z, q2); q3 = fmaf(v.w, v.w, q3);
  }
  atomicAdd(&ssum[c4 + 0], s0); atomicAdd(&ssum[c4 + 1], s1);
  atomicAdd(&ssum[c4 + 2], s2); atomicAdd(&ssum[c4 + 3], s3);
  atomicAdd(&ssq[c4 + 0], q0); atomicAdd(&ssq[c4 + 1], q1);
  atomicAdd(&ssq[c4 + 2], q2); atomicAdd(&ssq[c4 + 3], q3);
  __syncthreads();
  for (int c = threadIdx.x; c < Cdim; c += 256) {
    atomicAdd(&stats[c], ssum[c]);
    atomicAdd(&stats[512 + c], ssq[c]);
  }
}

__global__ void mk_bnfin(const float* __restrict__ stats, const float* __restrict__ g,
                         const float* __restrict__ beta, float* __restrict__ bn,
                         float Minv, int Cdim) {
  int c = blockIdx.x * blockDim.x + threadIdx.x;
  if (c >= Cdim) return;
  float mu = stats[c] * Minv;
  float var = stats[512 + c] * Minv - mu * mu;
  float a = g[c] * rsqrtf(var + BN_EPS);
  bn[c] = a;
  bn[512 + c] = beta[c] - a * mu;
}

__global__ void mk_maxpool(const float* __restrict__ h, const float* __restrict__ bn,
                           float* __restrict__ xo, int Npts, int Cdim) {
  int gid = blockIdx.x * blockDim.x + threadIdx.x;
  if (gid >= Npts * Cdim) return;
  int i = gid / Cdim, c = gid % Cdim;
  float a = bn[c], b = bn[512 + c];
  float m = -1e30f;
  const float* p = &h[(size_t)i * 32 * Cdim + c];
  for (int j = 0; j < 32; ++j) m = fmaxf(m, fmaf(a, p[(size_t)j * Cdim], b));
  xo[gid] = m;
}

__global__ void mk_deg(const int* __restrict__ col, float* __restrict__ deg, int E) {
  int e = blockIdx.x * blockDim.x + threadIdx.x;
  if (e < E) atomicAdd(&deg[col[e]], 1.f);
}
__global__ void mk_dinv(float* __restrict__ deg, int Npts) {
  int i = blockIdx.x * blockDim.x + threadIdx.x;
  if (i >= Npts) return;
  float d = deg[i];
  deg[i] = (d > 0.f) ? rsqrtf(fmaxf(d, 1.f)) : 0.f;
}
__global__ void mk_norm(const int* __restrict__ row, const int* __restrict__ col,
                        const float* __restrict__ dinv, float* __restrict__ nrm, int E) {
  int e = blockIdx.x * blockDim.x + threadIdx.x;
  if (e < E) nrm[e] = dinv[row[e]] * dinv[col[e]];
}
__global__ void mk_prop(const float* __restrict__ h, const int* __restrict__ row,
                        const int* __restrict__ col, const float* __restrict__ nrm,
                        float* __restrict__ out, int E, int Cdim) {
  int G = Cdim >> 2;
  int gid = blockIdx.x * blockDim.x + threadIdx.x;
  if (gid >= E * G) return;
  int e = gid / G, c4 = (gid % G) * 4;
  float w = nrm[e];
  int r = row[e], cl = col[e];
  float4 v = *(const float4*)&h[(size_t)r * Cdim + c4];
  float* o = &out[(size_t)cl * Cdim + c4];
  atomicAdd(&o[0], w * v.x); atomicAdd(&o[1], w * v.y);
  atomicAdd(&o[2], w * v.z); atomicAdd(&o[3], w * v.w);
}

__global__ __launch_bounds__(256)
void mk_gemv_out(const float* __restrict__ h, const float* __restrict__ bn,
                 const float* __restrict__ w, const float* __restrict__ b,
                 float* __restrict__ out, int Npts) {
  int row = blockIdx.x * 4 + (threadIdx.x >> 6);
  int lane = threadIdx.x & 63;
  if (row >= Npts) return;
  int c = lane * 4;
  float4 v = *(const float4*)&h[(size_t)row * 256 + c];
  float s = (bn[c] * v.x + bn[512 + c]) * w[c]
          + (bn[c + 1] * v.y + bn[512 + c + 1]) * w[c + 1]
          + (bn[c + 2] * v.z + bn[512 + c + 2]) * w[c + 2]
          + (bn[c + 3] * v.w + bn[512 + c + 3]) * w[c + 3];
#pragma unroll
  for (int off = 32; off; off >>= 1) s += __shfl_xor(s, off, 64);
  if (lane == 0) out[row] = s + b[0];
}

// ---------------- host ----------------
extern "C" void kernel_launch(void* const* d_in, const int* in_sizes, int n_in,
                              void* d_out, int out_size, void* d_ws, size_t ws_size,
                              hipStream_t stream) {
  const int N = 8192;
  const int NE = N * 32;  // 262144 edge messages
  const float* pos = (const float*)d_in[0];
  const float* xin = (const float*)d_in[1];
  const int* ei = (const int*)d_in[2];
  const int E = in_sizes[2] / 2;
  const int* erow = ei;
  const int* ecol = ei + E;
  const float* mlp1_W1  = (const float*)d_in[3];
  const float* mlp1_W23 = (const float*)d_in[4];
  const float* mlp1_b   = (const float*)d_in[5];
  const float* mlp1_g   = (const float*)d_in[6];
  const float* mlp1_be  = (const float*)d_in[7];
  const float* mlp2_W   = (const float*)d_in[8];
  const float* mlp2_b   = (const float*)d_in[9];
  const float* mlp2_g   = (const float*)d_in[10];
  const float* mlp2_be  = (const float*)d_in[11];
  const float* lin1_W   = (const float*)d_in[12];
  const float* lin1_b   = (const float*)d_in[13];
  const float* lin1_g   = (const float*)d_in[14];
  const float* lin1_be  = (const float*)d_in[15];
  const float* tag1_W   = (const float*)d_in[16];
  const float* tag1_b   = (const float*)d_in[17];
  const float* tag2_W   = (const float*)d_in[18];
  const float* tag2_b   = (const float*)d_in[19];
  const float* lin2_W   = (const float*)d_in[20];
  const float* lin2_b   = (const float*)d_in[21];
  const float* lin2_g   = (const float*)d_in[22];
  const float* lin2_be  = (const float*)d_in[23];
  const float* mix1_W   = (const float*)d_in[24];
  const float* mix1_b   = (const float*)d_in[25];
  const float* mix1_g   = (const float*)d_in[26];
  const float* mix1_be  = (const float*)d_in[27];
  const float* mix2_W   = (const float*)d_in[28];
  const float* mix2_b   = (const float*)d_in[29];
  const float* mix2_g   = (const float*)d_in[30];
  const float* mix2_be  = (const float*)d_in[31];
  const float* outW     = (const float*)d_in[32];
  const float* outB     = (const float*)d_in[33];

  char* base = (char*)d_ws;
  size_t off = 0;
  auto alloc = [&](size_t b) -> void* {
    void* p = base + off;
    off += (b + 255) & ~(size_t)255;
    return p;
  };
  // 128 MB phase-shared slab
  float* BIG = (float*)alloc(134217728ull);
  float* hA = BIG;                  // mlp1 ping (64 MB)
  float* hB = BIG + 16777216;       // mlp1 pong (64 MB)
  float* Sb = BIG;                  // knn2 S chunk (64 MB)
  float* hC = BIG;                  // mlp2 h (128 MB)
  float* out_dg = BIG;              // [8192,512] 16 MB (after mlp2 done)
  float* out_g  = BIG + 4194304;
  float* mh1    = BIG + 8388608;
  float* mh2    = BIG + 12582912;
  int*   idx1 = (int*)alloc((size_t)NE * 4);
  unsigned int* st_k = (unsigned int*)alloc((size_t)NE * 4);
  int*   st_i = (int*)alloc((size_t)NE * 4);
  float* x1  = (float*)alloc((size_t)N * 64 * 4);
  float* x2  = (float*)alloc((size_t)N * 128 * 4);
  float* g1  = (float*)alloc((size_t)N * 64 * 4);
  float* g2  = (float*)alloc((size_t)N * 128 * 4);
  float* x1T = (float*)alloc((size_t)N * 64 * 4);
  float* sqp = (float*)alloc((size_t)N * 4);
  float* sqx = (float*)alloc((size_t)N * 4);
  float* dinv = (float*)alloc((size_t)N * 4);
  float* enorm = (float*)alloc((size_t)E * 4);
  float* tpa = (float*)alloc((size_t)N * 64 * 4);
  float* tpb = (float*)alloc((size_t)N * 64 * 4);
  float* stats = (float*)alloc(1024 * 4);
  float* bnb = (float*)alloc(8 * 1024 * 4);
  auto bn = [&](int i) { return bnb + (size_t)i * 1024; };

  auto gemm = [&](const float* A, const float* src, const int* gidx, int srcC,
                  const float* bnA, const float* W, int ldw, const float* bias,
                  float* Cp, int ldc, int M, int Nn, int Kk, int flags) {
    dim3 g(M / 64, (Nn + 63) / 64);
    mk_gemm<<<g, 256, 0, stream>>>(A, src, gidx, srcC, bnA, W, ldw, bias, Cp, ldc, M, Nn, Kk, flags);
  };
  auto statsbn = [&](const float* h, int M, int C, const float* gg, const float* bb, float* bno) {
    hipMemsetAsync(stats, 0, 4096, stream);
    int RPB = (M + 127) / 128;
    mk_stats<<<128, 256, 0, stream>>>(h, stats, M, C, RPB);
    mk_bnfin<<<(C + 255) / 256, 256, 0, stream>>>(stats, gg, bb, bno, 1.f / M, C);
  };

  // ---- kNN-1 on pos ----
  mk_sqnorm<<<32, 256, 0, stream>>>(pos, sqp, N, 3);
  mk_knn1<<<N, 256, 0, stream>>>(pos, sqp, idx1, N);

  // ---- edge MLP1 (6->64->64->64, BN batch stats over 262144 rows) ----
  gemm(nullptr, pos, idx1, 3, nullptr, mlp1_W1, 64, mlp1_b, hA, 64, NE, 64, 6, 4 | 2);
  statsbn(hA, NE, 64, mlp1_g, mlp1_be, bn(0));
  gemm(hA, nullptr, nullptr, 0, bn(0), mlp1_W23, 64, mlp1_b + 64, hB, 64, NE, 64, 64, 2);
  statsbn(hB, NE, 64, mlp1_g + 64, mlp1_be + 64, bn(1));
  gemm(hB, nullptr, nullptr, 0, bn(1), mlp1_W23 + 4096, 64, mlp1_b + 128, hA, 64, NE, 64, 64, 2);
  statsbn(hA, NE, 64, mlp1_g + 128, mlp1_be + 128, bn(2));
  mk_maxpool<<<(N * 64) / 256, 256, 0, stream>>>(hA, bn(2), x1, N, 64);

  // ---- kNN-2 on x1 (chunked S = x1 @ x1^T) ----
  mk_sqnorm<<<32, 256, 0, stream>>>(x1, sqx, N, 64);
  mk_transpose<<<(N * 64) / 256, 256, 0, stream>>>(x1, x1T, N, 64);
  for (int c = 0; c < 4; ++c) {
    gemm(x1, nullptr, nullptr, 0, nullptr, x1T + c * 2048, N, nullptr, Sb, 2048, N, 2048, 64, 0);
    mk_knn2<<<N, 256, 0, stream>>>(Sb, sqx, c * 2048, 2048, c == 0 ? 1 : 0, st_k, st_i, N);
  }

  // ---- edge MLP2 (128->128) ----
  gemm(nullptr, x1, st_i, 64, nullptr, mlp2_W, 128, mlp2_b, hC, 128, NE, 128, 128, 4 | 2);
  statsbn(hC, NE, 128, mlp2_g, mlp2_be, bn(3));
  mk_maxpool<<<(N * 128) / 256, 256, 0, stream>>>(hC, bn(3), x2, N, 128);

  // ---- lin1: [x1,x2] -> 512 ----
  gemm(x1, nullptr, nullptr, 0, nullptr, lin1_W, 512, nullptr, out_dg, 512, N, 512, 64, 0);
  gemm(x2, nullptr, nullptr, 0, nullptr, lin1_W + 64 * 512, 512, lin1_b, out_dg, 512, N, 512, 128, 1 | 2);
  statsbn(out_dg, N, 512, lin1_g, lin1_be, bn(4));

  // ---- TAG branch ----
  hipMemsetAsync(dinv, 0, (size_t)N * 4, stream);
  mk_deg<<<(E + 255) / 256, 256, 0, stream>>>(ecol, dinv, E);
  mk_dinv<<<32, 256, 0, stream>>>(dinv, N);
  mk_norm<<<(E + 255) / 256, 256, 0, stream>>>(erow, ecol, dinv, enorm, E);
  // tag1 (C=4 -> 64)
  gemm(xin, nullptr, nullptr, 0, nullptr, tag1_W, 64, tag1_b, g1, 64, N, 64, 4, 0);
  hipMemsetAsync(tpb, 0, (size_t)N * 4 * 4, stream);
  mk_prop<<<(E + 255) / 256, 256, 0, stream>>>(xin, erow, ecol, enorm, tpb, E, 4);
  gemm(tpb, nullptr, nullptr, 0, nullptr, tag1_W + 256, 64, nullptr, g1, 64, N, 64, 4, 1);
  hipMemsetAsync(tpa, 0, (size_t)N * 4 * 4, stream);
  mk_prop<<<(E + 255) / 256, 256, 0, stream>>>(tpb, erow, ecol, enorm, tpa, E, 4);
  gemm(tpa, nullptr, nullptr, 0, nullptr, tag1_W + 512, 64, nullptr, g1, 64, N, 64, 4, 1);
  hipMemsetAsync(tpb, 0, (size_t)N * 4 * 4, stream);
  mk_prop<<<(E + 255) / 256, 256, 0, stream>>>(tpa, erow, ecol, enorm, tpb, E, 4);
  gemm(tpb, nullptr, nullptr, 0, nullptr, tag1_W + 768, 64, nullptr, g1, 64, N, 64, 4, 1 | 2);
  // tag2 (C=64 -> 128)
  gemm(g1, nullptr, nullptr, 0, nullptr, tag2_W, 128, tag2_b, g2, 128, N, 128, 64, 0);
  hipMemsetAsync(tpa, 0, (size_t)N * 64 * 4, stream);
  mk_prop<<<(E * 16 + 255) / 256, 256, 0, stream>>>(g1, erow, ecol, enorm, tpa, E, 64);
  gemm(tpa, nullptr, nullptr, 0, nullptr, tag2_W + 8192, 128, nullptr, g2, 128, N, 128, 64, 1);
  hipMemsetAsync(tpb, 0, (size_t)N * 64 * 4, stream);
  mk_prop<<<(E * 16 + 255) / 256, 256, 0, stream>>>(tpa, erow, ecol, enorm, tpb, E, 64);
  gemm(tpb, nullptr, nullptr, 0, nullptr, tag2_W + 16384, 128, nullptr, g2, 128, N, 128, 64, 1);
  hipMemsetAsync(tpa, 0, (size_t)N * 64 * 4, stream);
  mk_prop<<<(E * 16 + 255) / 256, 256, 0, stream>>>(tpb, erow, ecol, enorm, tpa, E, 64);
  gemm(tpa, nullptr, nullptr, 0, nullptr, tag2_W + 24576, 128, nullptr, g2, 128, N, 128, 64, 1 | 2);
  // lin2
  gemm(g1, nullptr, nullptr, 0, nullptr, lin2_W, 512, nullptr, out_g, 512, N, 512, 64, 0);
  gemm(g2, nullptr, nullptr, 0, nullptr, lin2_W + 64 * 512, 512, lin2_b, out_g, 512, N, 512, 128, 1 | 2);
  statsbn(out_g, N, 512, lin2_g, lin2_be, bn(5));

  // ---- mix head ----
  gemm(out_dg, nullptr, nullptr, 0, bn(4), mix1_W, 512, nullptr, mh1, 512, N, 512, 512, 0);
  gemm(out_g, nullptr, nullptr, 0, bn(5), mix1_W + 512 * 512, 512, mix1_b, mh1, 512, N, 512, 512, 1 | 2);
  statsbn(mh1, N, 512, mix1_g, mix1_be, bn(6));
  gemm(mh1, nullptr, nullptr, 0, bn(6), mix2_W, 256, mix2_b, mh2, 256, N, 256, 512, 2);
  statsbn(mh2, N, 256, mix2_g, mix2_be, bn(7));
  mk_gemv_out<<<N / 4, 256, 0, stream>>>(mh2, bn(7), outW, outB, (float*)d_out, N);
}

// Round 4
// 1876.314 us; speedup vs baseline: 3.1677x; 1.7444x over previous
//
#include <hip/hip_runtime.h>
#include <cstdint>
#include <cstddef>

#define BN_EPS 1e-5f
#define KB 2048
#define MAXB2 1024

typedef short short8 __attribute__((ext_vector_type(8)));
typedef float f32x4 __attribute__((ext_vector_type(4)));

// ---------------- helpers ----------------
__device__ __forceinline__ unsigned int ordf(float d) {
  unsigned int u = __float_as_uint(d);
  return (u >> 31) ? ~u : (u | 0x80000000u);
}
__device__ __forceinline__ unsigned short f2bf(float f) {
  unsigned u = __float_as_uint(f);
  u += 0x7fffu + ((u >> 16) & 1u);
  return (unsigned short)(u >> 16);
}
__device__ __forceinline__ float bf2f(unsigned short h) {
  return __uint_as_float(((unsigned)h) << 16);
}

// ---------------- MFMA bf16x3 GEMM ----------------
// C[M,N] = [ACC? C +] OP(A) @ W + bias, optional relu.
// A-source priority: A8h/A8l (pre-converted bf16 hi/lo, row-major [M][K]) ->
//   gather (flags&4: row r: i=r>>5, j=gidx[r]; [src_i, src_j - src_i]) ->
//   plain fp32 A [M][K] with optional bnA affine (bnA[k]*v + bnA[512+k]).
// W: pre-converted bf16 hi/lo, n-major [N][ldk], k index = koff + k.
// Requires M%64==0, N%64==0, K%32==0.
#define MPAD 40

__global__ __launch_bounds__(256)
void mk_gemm_mfma(const float* __restrict__ A,
                  const short* __restrict__ A8h, const short* __restrict__ A8l,
                  const float* __restrict__ src, const int* __restrict__ gidx, int srcC,
                  const float* __restrict__ bnA,
                  const short* __restrict__ Wh, const short* __restrict__ Wl,
                  int ldk, int koff,
                  const float* __restrict__ bias,
                  float* __restrict__ C, int ldc,
                  int M, int N, int K, int flags) {
  __shared__ short Ah[64][MPAD], Al[64][MPAD], Bh[64][MPAD], Bl[64][MPAD];
  int tid = threadIdx.x, lane = tid & 63, wid = tid >> 6;
  int wr = wid >> 1, wc = wid & 1;
  int r0 = blockIdx.x * 64, n0 = blockIdx.y * 64;
  f32x4 zero4 = {0.f, 0.f, 0.f, 0.f};
  f32x4 acc[2][2] = {{zero4, zero4}, {zero4, zero4}};
  int bn = tid >> 2, bk = (tid & 3) * 8;
  for (int kt = 0; kt < K; kt += 32) {
    if (A8h) {
      *(short8*)&Ah[bn][bk] = *(const short8*)&A8h[(size_t)(r0 + bn) * K + kt + bk];
      *(short8*)&Al[bn][bk] = *(const short8*)&A8l[(size_t)(r0 + bn) * K + kt + bk];
    } else {
#pragma unroll
      for (int it = 0; it < 8; ++it) {
        int idx = it * 256 + tid;
        int r = idx >> 5, k = idx & 31;
        int gr = r0 + r, gk = kt + k;
        float v;
        if (flags & 4) {
          int i = gr >> 5;
          if (gk < srcC) v = src[(size_t)i * srcC + gk];
          else {
            int j = gidx[gr]; int c = gk - srcC;
            v = src[(size_t)j * srcC + c] - src[(size_t)i * srcC + c];
          }
        } else {
          v = A[(size_t)gr * K + gk];
          if (bnA) v = fmaf(bnA[gk], v, bnA[512 + gk]);
        }
        unsigned short h = f2bf(v);
        Ah[r][k] = (short)h;
        Al[r][k] = (short)f2bf(v - bf2f(h));
      }
    }
    *(short8*)&Bh[bn][bk] = *(const short8*)&Wh[(size_t)(n0 + bn) * ldk + koff + kt + bk];
    *(short8*)&Bl[bn][bk] = *(const short8*)&Wl[(size_t)(n0 + bn) * ldk + koff + kt + bk];
    __syncthreads();
    int ar = wr * 32 + (lane & 15);
    int br = wc * 32 + (lane & 15);
    int kof = (lane >> 4) * 8;
    short8 a_h[2], a_l[2], b_h[2], b_l[2];
#pragma unroll
    for (int t = 0; t < 2; ++t) {
      a_h[t] = *(const short8*)&Ah[ar + t * 16][kof];
      a_l[t] = *(const short8*)&Al[ar + t * 16][kof];
      b_h[t] = *(const short8*)&Bh[br + t * 16][kof];
      b_l[t] = *(const short8*)&Bl[br + t * 16][kof];
    }
#pragma unroll
    for (int mt = 0; mt < 2; ++mt)
#pragma unroll
      for (int nt = 0; nt < 2; ++nt) {
        acc[mt][nt] = __builtin_amdgcn_mfma_f32_16x16x32_bf16(a_h[mt], b_h[nt], acc[mt][nt], 0, 0, 0);
        acc[mt][nt] = __builtin_amdgcn_mfma_f32_16x16x32_bf16(a_h[mt], b_l[nt], acc[mt][nt], 0, 0, 0);
        acc[mt][nt] = __builtin_amdgcn_mfma_f32_16x16x32_bf16(a_l[mt], b_h[nt], acc[mt][nt], 0, 0, 0);
      }
    __syncthreads();
  }
#pragma unroll
  for (int mt = 0; mt < 2; ++mt)
#pragma unroll
    for (int nt = 0; nt < 2; ++nt) {
      int gc = n0 + wc * 32 + nt * 16 + (lane & 15);
#pragma unroll
      for (int i = 0; i < 4; ++i) {
        int gr = r0 + wr * 32 + mt * 16 + (lane >> 4) * 4 + i;
        float v = acc[mt][nt][i];
        if (bias) v += bias[gc];
        if (flags & 1) v += C[(size_t)gr * ldc + gc];
        if (flags & 2) v = fmaxf(v, 0.f);
        C[(size_t)gr * ldc + gc] = v;
      }
    }
}

// ---------------- weight/activation bf16 hi/lo conversion ----------------
__global__ void mk_wcvt(const float* __restrict__ W, short* __restrict__ Wh,
                        short* __restrict__ Wl, int K, int N) {
  int g = blockIdx.x * 256 + threadIdx.x;
  if (g >= K * N) return;
  int k = g / N, n = g - k * N;
  float v = W[g];
  unsigned short h = f2bf(v);
  Wh[(size_t)n * K + k] = (short)h;
  Wl[(size_t)n * K + k] = (short)f2bf(v - bf2f(h));
}
__global__ void mk_cvt(const float* __restrict__ x, short* __restrict__ xh,
                       short* __restrict__ xl, int n) {
  int g = blockIdx.x * 256 + threadIdx.x;
  if (g >= n) return;
  float v = x[g];
  unsigned short h = f2bf(v);
  xh[g] = (short)h;
  xl[g] = (short)f2bf(v - bf2f(h));
}

// ---------------- kNN selection (register keys + 1-level histogram) ----------------
struct KCtl { unsigned B1, cum1, B2, cum2, acc, bnd; };

__device__ __forceinline__ void find_bin(const unsigned* hist, unsigned target,
                                         unsigned* outB, unsigned* outCum) {
  int lane = threadIdx.x;
  unsigned run = 0;
  for (int c = 0; c < KB / 64; ++c) {
    unsigned v = hist[c * 64 + lane];
    unsigned s = v;
#pragma unroll
    for (int off = 1; off < 64; off <<= 1) {
      unsigned t = __shfl_up(s, off, 64);
      if (lane >= off) s += t;
    }
    unsigned tot = __shfl(s, 63, 64);
    if (run + tot >= target) {
      unsigned long long mask = __ballot((run + s) >= target);
      int first = __ffsll((unsigned long long)mask) - 1;
      unsigned vf = __shfl(v, first, 64);
      unsigned sf = __shfl(s, first, 64);
      if (lane == 0) { *outB = (unsigned)(c * 64 + first); *outCum = run + sf - vf; }
      return;
    }
    run += tot;
  }
  if (lane == 0) { *outB = KB - 1; *outCum = run; }
}

__global__ __launch_bounds__(256)
void mk_knn1(const float* __restrict__ pos, const float* __restrict__ sq,
             int* __restrict__ idxout) {
  __shared__ unsigned hist[KB];
  __shared__ unsigned long long bbuf[MAXB2];
  __shared__ KCtl ctl;
  int q = blockIdx.x, tid = threadIdx.x;
  for (int b = tid; b < KB; b += 256) hist[b] = 0;
  if (tid == 0) { ctl.acc = 0; ctl.bnd = 0; }
  float qx = pos[q * 3], qy = pos[q * 3 + 1], qz = pos[q * 3 + 2], sqq = sq[q];
  unsigned key[32];
  __syncthreads();
#pragma unroll
  for (int c = 0; c < 32; ++c) {
    int j = c * 256 + tid;
    float d = sqq + sq[j] - 2.f * (qx * pos[j * 3] + qy * pos[j * 3 + 1] + qz * pos[j * 3 + 2]);
    unsigned k = (j == q) ? 0xFFFFFFFFu : ordf(d);
    key[c] = k;
    atomicAdd(&hist[k >> 21], 1u);
  }
  __syncthreads();
  if (tid < 64) find_bin(hist, 32u, &ctl.B1, &ctl.cum1);
  __syncthreads();
  unsigned B1 = ctl.B1, cum1 = ctl.cum1;
  int refine = hist[B1] > MAXB2;
  unsigned B2 = 0;
  if (refine) {
    __syncthreads();
    for (int b = tid; b < KB; b += 256) hist[b] = 0;
    __syncthreads();
#pragma unroll
    for (int c = 0; c < 32; ++c)
      if ((key[c] >> 21) == B1) atomicAdd(&hist[(key[c] >> 10) & 0x7FFu], 1u);
    __syncthreads();
    if (tid < 64) find_bin(hist, 32u - cum1, &ctl.B2, &ctl.cum2);
    __syncthreads();
    B2 = ctl.B2;
  }
#pragma unroll
  for (int c = 0; c < 32; ++c) {
    unsigned k = key[c];
    unsigned b = k >> 21;
    int j = c * 256 + tid;
    bool acc_e, bnd_e;
    if (!refine) { acc_e = b < B1; bnd_e = (b == B1); }
    else {
      unsigned l2 = (k >> 10) & 0x7FFu;
      acc_e = (b < B1) || (b == B1 && l2 < B2);
      bnd_e = (b == B1 && l2 == B2);
    }
    if (acc_e) { unsigned s = atomicAdd(&ctl.acc, 1u); idxout[q * 32 + s] = j; }
    else if (bnd_e) {
      unsigned s = atomicAdd(&ctl.bnd, 1u);
      if (s < MAXB2) bbuf[s] = (((unsigned long long)k) << 32) | (unsigned)j;
    }
  }
  __syncthreads();
  int acc = (int)ctl.acc, need = 32 - acc;
  int m = (int)ctl.bnd; if (m > MAXB2) m = MAXB2;
  for (int e = tid; e < m; e += 256) {
    unsigned long long me = bbuf[e];
    int rank = 0;
    for (int f = 0; f < m; ++f) rank += (bbuf[f] < me) ? 1 : 0;
    if (rank < need) idxout[q * 32 + acc + rank] = (int)(unsigned)(me & 0xFFFFFFFFu);
  }
}

__global__ __launch_bounds__(256)
void mk_knn2(const float* __restrict__ S, const float* __restrict__ sq,
             int c0, int first,
             unsigned* __restrict__ st_k, int* __restrict__ st_i) {
  __shared__ unsigned hist[KB];
  __shared__ unsigned long long bbuf[MAXB2];
  __shared__ KCtl ctl;
  int q = blockIdx.x, tid = threadIdx.x;
  for (int b = tid; b < KB; b += 256) hist[b] = 0;
  if (tid == 0) { ctl.acc = 0; ctl.bnd = 0; }
  float sqq = sq[q];
  unsigned key[8];
  unsigned ckey = 0xFFFFFFFFu; int cj = 0;
  int hascarry = (tid < 32) && !first;
  if (hascarry) { ckey = st_k[q * 32 + tid]; cj = st_i[q * 32 + tid]; }
  __syncthreads();
#pragma unroll
  for (int c = 0; c < 8; ++c) {
    int t = c * 256 + tid;
    int j = c0 + t;
    float d = sqq + sq[j] - 2.f * S[(size_t)q * 2048 + t];
    unsigned k = (j == q) ? 0xFFFFFFFFu : ordf(d);
    key[c] = k;
    atomicAdd(&hist[k >> 21], 1u);
  }
  if (hascarry) atomicAdd(&hist[ckey >> 21], 1u);
  __syncthreads();
  if (tid < 64) find_bin(hist, 32u, &ctl.B1, &ctl.cum1);
  __syncthreads();
  unsigned B1 = ctl.B1, cum1 = ctl.cum1;
  int refine = hist[B1] > MAXB2;
  unsigned B2 = 0;
  if (refine) {
    __syncthreads();
    for (int b = tid; b < KB; b += 256) hist[b] = 0;
    __syncthreads();
#pragma unroll
    for (int c = 0; c < 8; ++c)
      if ((key[c] >> 21) == B1) atomicAdd(&hist[(key[c] >> 10) & 0x7FFu], 1u);
    if (hascarry && (ckey >> 21) == B1) atomicAdd(&hist[(ckey >> 10) & 0x7FFu], 1u);
    __syncthreads();
    if (tid < 64) find_bin(hist, 32u - cum1, &ctl.B2, &ctl.cum2);
    __syncthreads();
    B2 = ctl.B2;
  }
  auto classify = [&](unsigned k, int j) {
    unsigned b = k >> 21;
    bool acc_e, bnd_e;
    if (!refine) { acc_e = b < B1; bnd_e = (b == B1); }
    else {
      unsigned l2 = (k >> 10) & 0x7FFu;
      acc_e = (b < B1) || (b == B1 && l2 < B2);
      bnd_e = (b == B1 && l2 == B2);
    }
    if (acc_e) {
      unsigned s = atomicAdd(&ctl.acc, 1u);
      st_k[q * 32 + s] = k; st_i[q * 32 + s] = j;
    } else if (bnd_e) {
      unsigned s = atomicAdd(&ctl.bnd, 1u);
      if (s < MAXB2) bbuf[s] = (((unsigned long long)k) << 32) | (unsigned)j;
    }
  };
#pragma unroll
  for (int c = 0; c < 8; ++c) classify(key[c], c0 + c * 256 + tid);
  if (hascarry) classify(ckey, cj);
  __syncthreads();
  int acc = (int)ctl.acc, need = 32 - acc;
  int m = (int)ctl.bnd; if (m > MAXB2) m = MAXB2;
  for (int e = tid; e < m; e += 256) {
    unsigned long long me = bbuf[e];
    int rank = 0;
    for (int f = 0; f < m; ++f) rank += (bbuf[f] < me) ? 1 : 0;
    if (rank < need) {
      st_k[q * 32 + acc + rank] = (unsigned)(me >> 32);
      st_i[q * 32 + acc + rank] = (int)(unsigned)(me & 0xFFFFFFFFu);
    }
  }
}

// ---------------- fp32 GEMM (small-K paths) ----------------
#define GBM 64
#define GBN 64
#define GBK 16

__global__ __launch_bounds__(256)
void mk_gemm(const float* __restrict__ A, const float* __restrict__ src,
             const int* __restrict__ gidx, int srcC,
             const float* __restrict__ bnA,
             const float* __restrict__ W, int ldw,
             const float* __restrict__ bias,
             float* __restrict__ C, int ldc,
             int M, int N, int K, int flags) {
  __shared__ float As[GBK][GBM + 4];
  __shared__ float Ws[GBK][GBN];
  int tid = threadIdx.x;
  int r0 = blockIdx.x * GBM, n0 = blockIdx.y * GBN;
  int ty = tid >> 4, tx = tid & 15;
  float acc[4][4] = {};
  for (int kt = 0; kt < K; kt += GBK) {
#pragma unroll
    for (int it = 0; it < 4; ++it) {
      int l = it * 256 + tid;
      int r = l >> 4, kk = l & 15;
      int gr = r0 + r, gk = kt + kk;
      float v = 0.f;
      if (gk < K && gr < M) {
        if (flags & 4) {
          int i = gr >> 5;
          if (gk < srcC) v = src[(size_t)i * srcC + gk];
          else {
            int j = gidx[gr]; int c = gk - srcC;
            v = src[(size_t)j * srcC + c] - src[(size_t)i * srcC + c];
          }
        } else {
          v = A[(size_t)gr * K + gk];
          if (bnA) v = bnA[gk] * v + bnA[512 + gk];
        }
      }
      As[kk][r] = v;
      int kw = l >> 6, nw = l & 63;
      int gkw = kt + kw;
      Ws[kw][nw] = (gkw < K && (n0 + nw) < N) ? W[(size_t)gkw * ldw + n0 + nw] : 0.f;
    }
    __syncthreads();
#pragma unroll
    for (int kk = 0; kk < GBK; ++kk) {
      float4 a4 = *(const float4*)&As[kk][ty * 4];
      float4 b4 = *(const float4*)&Ws[kk][tx * 4];
      float av[4] = {a4.x, a4.y, a4.z, a4.w};
      float bv[4] = {b4.x, b4.y, b4.z, b4.w};
#pragma unroll
      for (int i = 0; i < 4; ++i)
#pragma unroll
        for (int j = 0; j < 4; ++j)
          acc[i][j] = fmaf(av[i], bv[j], acc[i][j]);
    }
    __syncthreads();
  }
#pragma unroll
  for (int i = 0; i < 4; ++i) {
    int gr = r0 + ty * 4 + i;
    if (gr >= M) continue;
#pragma unroll
    for (int j = 0; j < 4; ++j) {
      int gc = n0 + tx * 4 + j;
      if (gc >= N) continue;
      float v = acc[i][j];
      if (bias) v += bias[gc];
      if (flags & 1) v += C[(size_t)gr * ldc + gc];
      if (flags & 2) v = fmaxf(v, 0.f);
      C[(size_t)gr * ldc + gc] = v;
    }
  }
}

// ---------------- small utility kernels ----------------
__global__ void mk_sqnorm(const float* __restrict__ x, float* __restrict__ sq, int Npts, int Cdim) {
  int i = blockIdx.x * blockDim.x + threadIdx.x;
  if (i >= Npts) return;
  float s = 0.f;
  for (int c = 0; c < Cdim; ++c) { float v = x[(size_t)i * Cdim + c]; s = fmaf(v, v, s); }
  sq[i] = s;
}

__global__ __launch_bounds__(256)
void mk_stats(const float* __restrict__ h, float* __restrict__ stats, int M, int Cdim, int RPB) {
  __shared__ float ssum[512], ssq[512];
  for (int c = threadIdx.x; c < Cdim; c += 256) { ssum[c] = 0.f; ssq[c] = 0.f; }
  __syncthreads();
  int G = Cdim >> 2;
  int c4 = (threadIdx.x % G) * 4;
  int rsub = threadIdx.x / G;
  int step = 256 / G;
  int r0 = blockIdx.x * RPB;
  int r1 = r0 + RPB; if (r1 > M) r1 = M;
  float s0 = 0, s1 = 0, s2 = 0, s3 = 0, q0 = 0, q1 = 0, q2 = 0, q3 = 0;
  for (int r = r0 + rsub; r < r1; r += step) {
    float4 v = *(const float4*)&h[(size_t)r * Cdim + c4];
    s0 += v.x; s1 += v.y; s2 += v.z; s3 += v.w;
    q0 = fmaf(v.x, v.x, q0); q1 = fmaf(v.y, v.y, q1);
    q2 = fmaf(v.z, v.z, q2); q3 = fmaf(v.w, v.w, q3);
  }
  atomicAdd(&ssum[c4 + 0], s0); atomicAdd(&ssum[c4 + 1], s1);
  atomicAdd(&ssum[c4 + 2], s2); atomicAdd(&ssum[c4 + 3], s3);
  atomicAdd(&ssq[c4 + 0], q0); atomicAdd(&ssq[c4 + 1], q1);
  atomicAdd(&ssq[c4 + 2], q2); atomicAdd(&ssq[c4 + 3], q3);
  __syncthreads();
  for (int c = threadIdx.x; c < Cdim; c += 256) {
    atomicAdd(&stats[c], ssum[c]);
    atomicAdd(&stats[512 + c], ssq[c]);
  }
}

__global__ void mk_bnfin(const float* __restrict__ stats, const float* __restrict__ g,
                         const float* __restrict__ beta, float* __restrict__ bn,
                         float Minv, int Cdim) {
  int c = blockIdx.x * blockDim.x + threadIdx.x;
  if (c >= Cdim) return;
  float mu = stats[c] * Minv;
  float var = stats[512 + c] * Minv - mu * mu;
  float a = g[c] * rsqrtf(var + BN_EPS);
  bn[c] = a;
  bn[512 + c] = beta[c] - a * mu;
}

__global__ void mk_maxpool(const float* __restrict__ h, const float* __restrict__ bn,
                           float* __restrict__ xo, int Npts, int Cdim) {
  int gid = blockIdx.x * blockDim.x + threadIdx.x;
  if (gid >= Npts * Cdim) return;
  int i = gid / Cdim, c = gid % Cdim;
  float a = bn[c], b = bn[512 + c];
  float m = -1e30f;
  const float* p = &h[(size_t)i * 32 * Cdim + c];
  for (int j = 0; j < 32; ++j) m = fmaxf(m, fmaf(a, p[(size_t)j * Cdim], b));
  xo[gid] = m;
}

__global__ void mk_deg(const int* __restrict__ col, float* __restrict__ deg, int E) {
  int e = blockIdx.x * blockDim.x + threadIdx.x;
  if (e < E) atomicAdd(&deg[col[e]], 1.f);
}
__global__ void mk_dinv(float* __restrict__ deg, int Npts) {
  int i = blockIdx.x * blockDim.x + threadIdx.x;
  if (i >= Npts) return;
  float d = deg[i];
  deg[i] = (d > 0.f) ? rsqrtf(fmaxf(d, 1.f)) : 0.f;
}
__global__ void mk_norm(const int* __restrict__ row, const int* __restrict__ col,
                        const float* __restrict__ dinv, float* __restrict__ nrm, int E) {
  int e = blockIdx.x * blockDim.x + threadIdx.x;
  if (e < E) nrm[e] = dinv[row[e]] * dinv[col[e]];
}
__global__ void mk_prop(const float* __restrict__ h, const int* __restrict__ row,
                        const int* __restrict__ col, const float* __restrict__ nrm,
                        float* __restrict__ out, int E, int Cdim) {
  int G = Cdim >> 2;
  int gid = blockIdx.x * blockDim.x + threadIdx.x;
  if (gid >= E * G) return;
  int e = gid / G, c4 = (gid % G) * 4;
  float w = nrm[e];
  int r = row[e], cl = col[e];
  float4 v = *(const float4*)&h[(size_t)r * Cdim + c4];
  float* o = &out[(size_t)cl * Cdim + c4];
  atomicAdd(&o[0], w * v.x); atomicAdd(&o[1], w * v.y);
  atomicAdd(&o[2], w * v.z); atomicAdd(&o[3], w * v.w);
}

__global__ __launch_bounds__(256)
void mk_gemv_out(const float* __restrict__ h, const float* __restrict__ bn,
                 const float* __restrict__ w, const float* __restrict__ b,
                 float* __restrict__ out, int Npts) {
  int row = blockIdx.x * 4 + (threadIdx.x >> 6);
  int lane = threadIdx.x & 63;
  if (row >= Npts) return;
  int c = lane * 4;
  float4 v = *(const float4*)&h[(size_t)row * 256 + c];
  float s = (bn[c] * v.x + bn[512 + c]) * w[c]
          + (bn[c + 1] * v.y + bn[512 + c + 1]) * w[c + 1]
          + (bn[c + 2] * v.z + bn[512 + c + 2]) * w[c + 2]
          + (bn[c + 3] * v.w + bn[512 + c + 3]) * w[c + 3];
#pragma unroll
  for (int off = 32; off; off >>= 1) s += __shfl_xor(s, off, 64);
  if (lane == 0) out[row] = s + b[0];
}

// ---------------- host ----------------
extern "C" void kernel_launch(void* const* d_in, const int* in_sizes, int n_in,
                              void* d_out, int out_size, void* d_ws, size_t ws_size,
                              hipStream_t stream) {
  const int N = 8192;
  const int NE = N * 32;
  const float* pos = (const float*)d_in[0];
  const float* xin = (const float*)d_in[1];
  const int* ei = (const int*)d_in[2];
  const int E = in_sizes[2] / 2;
  const int* erow = ei;
  const int* ecol = ei + E;
  const float* mlp1_W1  = (const float*)d_in[3];
  const float* mlp1_W23 = (const float*)d_in[4];
  const float* mlp1_b   = (const float*)d_in[5];
  const float* mlp1_g   = (const float*)d_in[6];
  const float* mlp1_be  = (const float*)d_in[7];
  const float* mlp2_W   = (const float*)d_in[8];
  const float* mlp2_b   = (const float*)d_in[9];
  const float* mlp2_g   = (const float*)d_in[10];
  const float* mlp2_be  = (const float*)d_in[11];
  const float* lin1_W   = (const float*)d_in[12];
  const float* lin1_b   = (const float*)d_in[13];
  const float* lin1_g   = (const float*)d_in[14];
  const float* lin1_be  = (const float*)d_in[15];
  const float* tag1_W   = (const float*)d_in[16];
  const float* tag1_b   = (const float*)d_in[17];
  const float* tag2_W   = (const float*)d_in[18];
  const float* tag2_b   = (const float*)d_in[19];
  const float* lin2_W   = (const float*)d_in[20];
  const float* lin2_b   = (const float*)d_in[21];
  const float* lin2_g   = (const float*)d_in[22];
  const float* lin2_be  = (const float*)d_in[23];
  const float* mix1_W   = (const float*)d_in[24];
  const float* mix1_b   = (const float*)d_in[25];
  const float* mix1_g   = (const float*)d_in[26];
  const float* mix1_be  = (const float*)d_in[27];
  const float* mix2_W   = (const float*)d_in[28];
  const float* mix2_b   = (const float*)d_in[29];
  const float* mix2_g   = (const float*)d_in[30];
  const float* mix2_be  = (const float*)d_in[31];
  const float* outW     = (const float*)d_in[32];
  const float* outB     = (const float*)d_in[33];

  char* base = (char*)d_ws;
  size_t off = 0;
  auto alloc = [&](size_t b) -> void* {
    void* p = base + off;
    off += (b + 255) & ~(size_t)255;
    return p;
  };
  float* BIG = (float*)alloc(134217728ull);
  float* hA = BIG;
  float* hB = BIG + 16777216;
  float* Sb = BIG;
  float* hC = BIG;
  float* out_dg = BIG;
  float* out_g  = BIG + 4194304;
  float* mh1    = BIG + 8388608;
  float* mh2    = BIG + 12582912;
  int*   idx1 = (int*)alloc((size_t)NE * 4);
  unsigned* st_k = (unsigned*)alloc((size_t)NE * 4);
  int*   st_i = (int*)alloc((size_t)NE * 4);
  float* x1  = (float*)alloc((size_t)N * 64 * 4);
  float* x2  = (float*)alloc((size_t)N * 128 * 4);
  float* g1  = (float*)alloc((size_t)N * 64 * 4);
  float* g2  = (float*)alloc((size_t)N * 128 * 4);
  float* sqp = (float*)alloc((size_t)N * 4);
  float* sqx = (float*)alloc((size_t)N * 4);
  float* dinv = (float*)alloc((size_t)N * 4);
  float* enorm = (float*)alloc((size_t)E * 4);
  float* tpa = (float*)alloc((size_t)N * 64 * 4);
  float* tpb = (float*)alloc((size_t)N * 64 * 4);
  float* stats8 = (float*)alloc(8 * 1024 * 4);
  float* bnb = (float*)alloc(8 * 1024 * 4);
  auto bnp = [&](int i) { return bnb + (size_t)i * 1024; };
  auto stp = [&](int i) { return stats8 + (size_t)i * 1024; };
  // bf16 hi/lo weight buffers (n-major [N][K])
  auto salloc = [&](size_t n) { return (short*)alloc(n * 2); };
  short* w23a_h = salloc(4096);   short* w23a_l = salloc(4096);
  short* w23b_h = salloc(4096);   short* w23b_l = salloc(4096);
  short* wm2_h  = salloc(16384);  short* wm2_l  = salloc(16384);
  short* wl1_h  = salloc(98304);  short* wl1_l  = salloc(98304);
  short* wt2_h  = salloc(32768);  short* wt2_l  = salloc(32768);
  short* wl2_h  = salloc(98304);  short* wl2_l  = salloc(98304);
  short* wx1_h  = salloc(524288); short* wx1_l  = salloc(524288);
  short* wx2_h  = salloc(131072); short* wx2_l  = salloc(131072);
  short* x1h    = salloc(524288); short* x1l    = salloc(524288);

  auto gemm = [&](const float* A, const float* src, const int* gidx, int srcC,
                  const float* bnA, const float* W, int ldw, const float* bias,
                  float* Cp, int ldc, int M, int Nn, int Kk, int flags) {
    dim3 g(M / 64, (Nn + 63) / 64);
    mk_gemm<<<g, 256, 0, stream>>>(A, src, gidx, srcC, bnA, W, ldw, bias, Cp, ldc, M, Nn, Kk, flags);
  };
  auto gemmF = [&](const float* A, const short* A8h, const short* A8l,
                   const float* src, const int* gidx, int srcC, const float* bnA,
                   const short* Wh_, const short* Wl_, int ldk, int koff,
                   const float* bias, float* Cp, int ldc,
                   int M, int Nn, int Kk, int flags) {
    dim3 g(M / 64, Nn / 64);
    mk_gemm_mfma<<<g, 256, 0, stream>>>(A, A8h, A8l, src, gidx, srcC, bnA,
                                        Wh_, Wl_, ldk, koff, bias, Cp, ldc, M, Nn, Kk, flags);
  };
  auto wcvt = [&](const float* W, short* Wh_, short* Wl_, int Kk, int Nn) {
    mk_wcvt<<<(Kk * Nn + 255) / 256, 256, 0, stream>>>(W, Wh_, Wl_, Kk, Nn);
  };
  auto statsbn = [&](const float* h, int M, int C, const float* gg, const float* bb,
                     float* st, float* bno) {
    mk_stats<<<128, 256, 0, stream>>>(h, st, M, C, (M + 127) / 128);
    mk_bnfin<<<(C + 255) / 256, 256, 0, stream>>>(st, gg, bb, bno, 1.f / M, C);
  };

  // ---- init + weight conversion ----
  hipMemsetAsync(stats8, 0, 8 * 1024 * 4, stream);
  wcvt(mlp1_W23,        w23a_h, w23a_l, 64, 64);
  wcvt(mlp1_W23 + 4096, w23b_h, w23b_l, 64, 64);
  wcvt(mlp2_W, wm2_h, wm2_l, 128, 128);
  wcvt(lin1_W, wl1_h, wl1_l, 192, 512);
  for (int hop = 0; hop < 4; ++hop)
    wcvt(tag2_W + hop * 8192, wt2_h + hop * 8192, wt2_l + hop * 8192, 64, 128);
  wcvt(lin2_W, wl2_h, wl2_l, 192, 512);
  wcvt(mix1_W, wx1_h, wx1_l, 1024, 512);
  wcvt(mix2_W, wx2_h, wx2_l, 512, 256);

  // ---- kNN-1 on pos ----
  mk_sqnorm<<<32, 256, 0, stream>>>(pos, sqp, N, 3);
  mk_knn1<<<N, 256, 0, stream>>>(pos, sqp, idx1);

  // ---- edge MLP1 (6->64->64->64) ----
  gemm(nullptr, pos, idx1, 3, nullptr, mlp1_W1, 64, mlp1_b, hA, 64, NE, 64, 6, 4 | 2);
  statsbn(hA, NE, 64, mlp1_g, mlp1_be, stp(0), bnp(0));
  gemmF(hA, nullptr, nullptr, nullptr, nullptr, 0, bnp(0),
        w23a_h, w23a_l, 64, 0, mlp1_b + 64, hB, 64, NE, 64, 64, 2);
  statsbn(hB, NE, 64, mlp1_g + 64, mlp1_be + 64, stp(1), bnp(1));
  gemmF(hB, nullptr, nullptr, nullptr, nullptr, 0, bnp(1),
        w23b_h, w23b_l, 64, 0, mlp1_b + 128, hA, 64, NE, 64, 64, 2);
  statsbn(hA, NE, 64, mlp1_g + 128, mlp1_be + 128, stp(2), bnp(2));
  mk_maxpool<<<(N * 64) / 256, 256, 0, stream>>>(hA, bnp(2), x1, N, 64);

  // ---- kNN-2 on x1 (chunked S = x1 @ x1^T via bf16x3 MFMA) ----
  mk_sqnorm<<<32, 256, 0, stream>>>(x1, sqx, N, 64);
  mk_cvt<<<(N * 64 + 255) / 256, 256, 0, stream>>>(x1, x1h, x1l, N * 64);
  for (int c = 0; c < 4; ++c) {
    gemmF(x1, x1h, x1l, nullptr, nullptr, 0, nullptr,
          x1h + (size_t)c * 2048 * 64, x1l + (size_t)c * 2048 * 64, 64, 0,
          nullptr, Sb, 2048, N, 2048, 64, 0);
    mk_knn2<<<N, 256, 0, stream>>>(Sb, sqx, c * 2048, c == 0 ? 1 : 0, st_k, st_i);
  }

  // ---- edge MLP2 (128->128, gather) ----
  gemmF(nullptr, nullptr, nullptr, x1, st_i, 64, nullptr,
        wm2_h, wm2_l, 128, 0, mlp2_b, hC, 128, NE, 128, 128, 4 | 2);
  statsbn(hC, NE, 128, mlp2_g, mlp2_be, stp(3), bnp(3));
  mk_maxpool<<<(N * 128) / 256, 256, 0, stream>>>(hC, bnp(3), x2, N, 128);

  // ---- lin1: [x1,x2] -> 512 ----
  gemmF(x1, x1h, x1l, nullptr, nullptr, 0, nullptr,
        wl1_h, wl1_l, 192, 0, nullptr, out_dg, 512, N, 512, 64, 0);
  gemmF(x2, nullptr, nullptr, nullptr, nullptr, 0, nullptr,
        wl1_h, wl1_l, 192, 64, lin1_b, out_dg, 512, N, 512, 128, 1 | 2);
  statsbn(out_dg, N, 512, lin1_g, lin1_be, stp(4), bnp(4));

  // ---- TAG branch ----
  hipMemsetAsync(dinv, 0, (size_t)N * 4, stream);
  mk_deg<<<(E + 255) / 256, 256, 0, stream>>>(ecol, dinv, E);
  mk_dinv<<<32, 256, 0, stream>>>(dinv, N);
  mk_norm<<<(E + 255) / 256, 256, 0, stream>>>(erow, ecol, dinv, enorm, E);
  gemm(xin, nullptr, nullptr, 0, nullptr, tag1_W, 64, tag1_b, g1, 64, N, 64, 4, 0);
  hipMemsetAsync(tpb, 0, (size_t)N * 4 * 4, stream);
  mk_prop<<<(E + 255) / 256, 256, 0, stream>>>(xin, erow, ecol, enorm, tpb, E, 4);
  gemm(tpb, nullptr, nullptr, 0, nullptr, tag1_W + 256, 64, nullptr, g1, 64, N, 64, 4, 1);
  hipMemsetAsync(tpa, 0, (size_t)N * 4 * 4, stream);
  mk_prop<<<(E + 255) / 256, 256, 0, stream>>>(tpb, erow, ecol, enorm, tpa, E, 4);
  gemm(tpa, nullptr, nullptr, 0, nullptr, tag1_W + 512, 64, nullptr, g1, 64, N, 64, 4, 1);
  hipMemsetAsync(tpb, 0, (size_t)N * 4 * 4, stream);
  mk_prop<<<(E + 255) / 256, 256, 0, stream>>>(tpa, erow, ecol, enorm, tpb, E, 4);
  gemm(tpb, nullptr, nullptr, 0, nullptr, tag1_W + 768, 64, nullptr, g1, 64, N, 64, 4, 1 | 2);
  // tag2 (64 -> 128)
  gemmF(g1, nullptr, nullptr, nullptr, nullptr, 0, nullptr,
        wt2_h, wt2_l, 64, 0, tag2_b, g2, 128, N, 128, 64, 0);
  hipMemsetAsync(tpa, 0, (size_t)N * 64 * 4, stream);
  mk_prop<<<(E * 16 + 255) / 256, 256, 0, stream>>>(g1, erow, ecol, enorm, tpa, E, 64);
  gemmF(tpa, nullptr, nullptr, nullptr, nullptr, 0, nullptr,
        wt2_h + 8192, wt2_l + 8192, 64, 0, nullptr, g2, 128, N, 128, 64, 1);
  hipMemsetAsync(tpb, 0, (size_t)N * 64 * 4, stream);
  mk_prop<<<(E * 16 + 255) / 256, 256, 0, stream>>>(tpa, erow, ecol, enorm, tpb, E, 64);
  gemmF(tpb, nullptr, nullptr, nullptr, nullptr, 0, nullptr,
        wt2_h + 16384, wt2_l + 16384, 64, 0, nullptr, g2, 128, N, 128, 64, 1);
  hipMemsetAsync(tpa, 0, (size_t)N * 64 * 4, stream);
  mk_prop<<<(E * 16 + 255) / 256, 256, 0, stream>>>(tpb, erow, ecol, enorm, tpa, E, 64);
  gemmF(tpa, nullptr, nullptr, nullptr, nullptr, 0, nullptr,
        wt2_h + 24576, wt2_l + 24576, 64, 0, nullptr, g2, 128, N, 128, 64, 1 | 2);
  // lin2
  gemmF(g1, nullptr, nullptr, nullptr, nullptr, 0, nullptr,
        wl2_h, wl2_l, 192, 0, nullptr, out_g, 512, N, 512, 64, 0);
  gemmF(g2, nullptr, nullptr, nullptr, nullptr, 0, nullptr,
        wl2_h, wl2_l, 192, 64, lin2_b, out_g, 512, N, 512, 128, 1 | 2);
  statsbn(out_g, N, 512, lin2_g, lin2_be, stp(5), bnp(5));

  // ---- mix head ----
  gemmF(out_dg, nullptr, nullptr, nullptr, nullptr, 0, bnp(4),
        wx1_h, wx1_l, 1024, 0, nullptr, mh1, 512, N, 512, 512, 0);
  gemmF(out_g, nullptr, nullptr, nullptr, nullptr, 0, bnp(5),
        wx1_h, wx1_l, 1024, 512, mix1_b, mh1, 512, N, 512, 512, 1 | 2);
  statsbn(mh1, N, 512, mix1_g, mix1_be, stp(6), bnp(6));
  gemmF(mh1, nullptr, nullptr, nullptr, nullptr, 0, bnp(6),
        wx2_h, wx2_l, 512, 0, mix2_b, mh2, 256, N, 256, 512, 2);
  statsbn(mh2, N, 256, mix2_g, mix2_be, stp(7), bnp(7));
  mk_gemv_out<<<N / 4, 256, 0, stream>>>(mh2, bnp(7), outW, outB, (float*)d_out, N);
}

// Round 5
// 1204.954 us; speedup vs baseline: 4.9327x; 1.5572x over previous
//
#include <hip/hip_runtime.h>
#include <cstdint>
#include <cstddef>

#define BN_EPS 1e-5f
#define KB 2048
#define MAXB2 1024

typedef short short8 __attribute__((ext_vector_type(8)));
typedef float f32x4 __attribute__((ext_vector_type(4)));

// ---------------- helpers ----------------
__device__ __forceinline__ unsigned int ordf(float d) {
  unsigned int u = __float_as_uint(d);
  return (u >> 31) ? ~u : (u | 0x80000000u);
}
__device__ __forceinline__ unsigned short f2bf(float f) {
  unsigned u = __float_as_uint(f);
  u += 0x7fffu + ((u >> 16) & 1u);
  return (unsigned short)(u >> 16);
}
__device__ __forceinline__ float bf2f(unsigned short h) {
  return __uint_as_float(((unsigned)h) << 16);
}

// ---------------- MFMA bf16x3 GEMM ----------------
// C[M,N] = [ACC? C +] OP(A) @ W + bias, optional relu.
// flags: 1=ACC, 2=RELU, 4=gather-A, 8=stats epilogue (slotted), 16=maxmin
// epilogue (per-node, NO C write), 32=EDGE1-A (v=relu(A[i][k]+src[j][k])).
// A-source priority: A8h/A8l bf16 hi/lo -> flags&32 -> flags&4 -> plain fp32+bnA.
// W: bf16 hi/lo n-major [N][ldk], k index = koff+k. M%64==0, N%64==0, K%32==0.
#define MPAD 40

__global__ __launch_bounds__(256)
void mk_gemm_mfma(const float* __restrict__ A,
                  const short* __restrict__ A8h, const short* __restrict__ A8l,
                  const float* __restrict__ src, const int* __restrict__ gidx, int srcC,
                  const float* __restrict__ bnA,
                  const short* __restrict__ Wh, const short* __restrict__ Wl,
                  int ldk, int koff,
                  const float* __restrict__ bias,
                  float* __restrict__ C, int ldc,
                  int M, int N, int K, int flags,
                  float* __restrict__ statsP,
                  float* __restrict__ mxp, float* __restrict__ mnp) {
  __shared__ short Ah[64][MPAD], Al[64][MPAD], Bh[64][MPAD], Bl[64][MPAD];
  __shared__ float ssum[64], ssq[64];
  int tid = threadIdx.x, lane = tid & 63, wid = tid >> 6;
  int wr = wid >> 1, wc = wid & 1;
  int r0 = blockIdx.x * 64, n0 = blockIdx.y * 64;
  f32x4 zero4 = {0.f, 0.f, 0.f, 0.f};
  f32x4 acc[2][2] = {{zero4, zero4}, {zero4, zero4}};
  int bn = tid >> 2, bk = (tid & 3) * 8;
  for (int kt = 0; kt < K; kt += 32) {
    if (A8h) {
      *(short8*)&Ah[bn][bk] = *(const short8*)&A8h[(size_t)(r0 + bn) * K + kt + bk];
      *(short8*)&Al[bn][bk] = *(const short8*)&A8l[(size_t)(r0 + bn) * K + kt + bk];
    } else {
#pragma unroll
      for (int it = 0; it < 8; ++it) {
        int idx = it * 256 + tid;
        int r = idx >> 5, k = idx & 31;
        int gr = r0 + r, gk = kt + k;
        float v;
        if (flags & 32) {
          int i = gr >> 5; int j = gidx[gr];
          v = fmaxf(A[(size_t)i * srcC + gk] + src[(size_t)j * srcC + gk], 0.f);
          if (bnA) v = fmaf(bnA[gk], v, bnA[512 + gk]);
        } else if (flags & 4) {
          int i = gr >> 5;
          if (gk < srcC) v = src[(size_t)i * srcC + gk];
          else {
            int j = gidx[gr]; int c = gk - srcC;
            v = src[(size_t)j * srcC + c] - src[(size_t)i * srcC + c];
          }
        } else {
          v = A[(size_t)gr * K + gk];
          if (bnA) v = fmaf(bnA[gk], v, bnA[512 + gk]);
        }
        unsigned short h = f2bf(v);
        Ah[r][k] = (short)h;
        Al[r][k] = (short)f2bf(v - bf2f(h));
      }
    }
    *(short8*)&Bh[bn][bk] = *(const short8*)&Wh[(size_t)(n0 + bn) * ldk + koff + kt + bk];
    *(short8*)&Bl[bn][bk] = *(const short8*)&Wl[(size_t)(n0 + bn) * ldk + koff + kt + bk];
    __syncthreads();
    int ar = wr * 32 + (lane & 15);
    int br = wc * 32 + (lane & 15);
    int kof = (lane >> 4) * 8;
    short8 a_h[2], a_l[2], b_h[2], b_l[2];
#pragma unroll
    for (int t = 0; t < 2; ++t) {
      a_h[t] = *(const short8*)&Ah[ar + t * 16][kof];
      a_l[t] = *(const short8*)&Al[ar + t * 16][kof];
      b_h[t] = *(const short8*)&Bh[br + t * 16][kof];
      b_l[t] = *(const short8*)&Bl[br + t * 16][kof];
    }
#pragma unroll
    for (int mt = 0; mt < 2; ++mt)
#pragma unroll
      for (int nt = 0; nt < 2; ++nt) {
        acc[mt][nt] = __builtin_amdgcn_mfma_f32_16x16x32_bf16(a_h[mt], b_h[nt], acc[mt][nt], 0, 0, 0);
        acc[mt][nt] = __builtin_amdgcn_mfma_f32_16x16x32_bf16(a_h[mt], b_l[nt], acc[mt][nt], 0, 0, 0);
        acc[mt][nt] = __builtin_amdgcn_mfma_f32_16x16x32_bf16(a_l[mt], b_h[nt], acc[mt][nt], 0, 0, 0);
      }
    __syncthreads();
  }
  bool dostat = (flags & 8) != 0, domx = (flags & 16) != 0;
  float lsum[2] = {0.f, 0.f}, lsq[2] = {0.f, 0.f};
  float lmx[2] = {-3.4e38f, -3.4e38f}, lmn[2] = {3.4e38f, 3.4e38f};
#pragma unroll
  for (int nt = 0; nt < 2; ++nt) {
    int gc = n0 + wc * 32 + nt * 16 + (lane & 15);
#pragma unroll
    for (int mt = 0; mt < 2; ++mt)
#pragma unroll
      for (int i = 0; i < 4; ++i) {
        int gr = r0 + wr * 32 + mt * 16 + (lane >> 4) * 4 + i;
        float v = acc[mt][nt][i];
        if (bias) v += bias[gc];
        if (flags & 1) v += C[(size_t)gr * ldc + gc];
        if (flags & 2) v = fmaxf(v, 0.f);
        if (!domx) C[(size_t)gr * ldc + gc] = v;
        lsum[nt] += v; lsq[nt] = fmaf(v, v, lsq[nt]);
        lmx[nt] = fmaxf(lmx[nt], v); lmn[nt] = fminf(lmn[nt], v);
      }
  }
  if (dostat || domx) {
#pragma unroll
    for (int nt = 0; nt < 2; ++nt) {
#pragma unroll
      for (int m = 16; m <= 32; m <<= 1) {
        lsum[nt] += __shfl_xor(lsum[nt], m, 64);
        lsq[nt] += __shfl_xor(lsq[nt], m, 64);
        lmx[nt] = fmaxf(lmx[nt], __shfl_xor(lmx[nt], m, 64));
        lmn[nt] = fminf(lmn[nt], __shfl_xor(lmn[nt], m, 64));
      }
    }
    if (domx && lane < 16) {
      int node = blockIdx.x * 2 + wr;
#pragma unroll
      for (int nt = 0; nt < 2; ++nt) {
        int gc = n0 + wc * 32 + nt * 16 + lane;
        mxp[(size_t)node * N + gc] = lmx[nt];
        mnp[(size_t)node * N + gc] = lmn[nt];
      }
    }
    if (dostat) {
      if (tid < 64) { ssum[tid] = 0.f; ssq[tid] = 0.f; }
      __syncthreads();
      if (lane < 16) {
#pragma unroll
        for (int nt = 0; nt < 2; ++nt) {
          int ct = wc * 32 + nt * 16 + lane;
          atomicAdd(&ssum[ct], lsum[nt]);
          atomicAdd(&ssq[ct], lsq[nt]);
        }
      }
      __syncthreads();
      if (tid < 64) {
        int slot = blockIdx.x & 63;
        int gc = n0 + tid;
        atomicAdd(&statsP[(size_t)slot * 1024 + gc], ssum[tid]);
        atomicAdd(&statsP[(size_t)slot * 1024 + 512 + gc], ssq[tid]);
      }
    }
  }
}

// ---------------- weight conversion ----------------
__global__ void mk_wcvt(const float* __restrict__ W, short* __restrict__ Wh,
                        short* __restrict__ Wl, int K, int N) {
  int g = blockIdx.x * 256 + threadIdx.x;
  if (g >= K * N) return;
  int k = g / N, n = g - k * N;
  float v = W[g];
  unsigned short h = f2bf(v);
  Wh[(size_t)n * K + k] = (short)h;
  Wl[(size_t)n * K + k] = (short)f2bf(v - bf2f(h));
}
// mlp2_W [128][128]: rows 0-63 = U, 64-127 = V. D = U-V, V separate; n-major [128][64].
__global__ void mk_wcvt2(const float* __restrict__ W, short* __restrict__ Dh,
                         short* __restrict__ Dl, short* __restrict__ Vh,
                         short* __restrict__ Vl) {
  int g = blockIdx.x * 256 + threadIdx.x;
  if (g >= 64 * 128) return;
  int k = g >> 7, n = g & 127;
  float u = W[k * 128 + n], vv = W[(64 + k) * 128 + n];
  float d = u - vv;
  unsigned short h = f2bf(d);
  Dh[n * 64 + k] = (short)h; Dl[n * 64 + k] = (short)f2bf(d - bf2f(h));
  h = f2bf(vv);
  Vh[n * 64 + k] = (short)h; Vl[n * 64 + k] = (short)f2bf(vv - bf2f(h));
}

// ---------------- conv1 node tables ----------------
// Pp[i][c] = pos_i @ (A-B) + b1[c], Q[i][c] = pos_i @ B  (A=W1[0:3], B=W1[3:6])
__global__ void mk_conv1nodes(const float* __restrict__ pos, const float* __restrict__ W1,
                              const float* __restrict__ b1, float* __restrict__ Pp,
                              float* __restrict__ Qn) {
  int g = blockIdx.x * 256 + threadIdx.x;
  if (g >= 8192 * 64) return;
  int i = g >> 6, c = g & 63;
  float p0 = pos[i * 3], p1 = pos[i * 3 + 1], p2 = pos[i * 3 + 2];
  float q = p0 * W1[192 + c] + p1 * W1[256 + c] + p2 * W1[320 + c];
  Qn[g] = q;
  Pp[g] = p0 * W1[c] + p1 * W1[64 + c] + p2 * W1[128 + c] - q + b1[c];
}

// ---------------- streaming stats of h1 = relu(Pp_i + Q_j) ----------------
__global__ __launch_bounds__(256)
void mk_stats1(const float* __restrict__ Pp, const float* __restrict__ Qn,
               const int* __restrict__ idx1, float* __restrict__ statsP) {
  __shared__ int sidx[512];
  int tid = threadIdx.x;
  int c = tid & 63, grp = tid >> 6;
  int nb = blockIdx.x * 16;
  if (tid < 256) {
    sidx[tid] = idx1[nb * 32 + tid];
    sidx[tid + 256] = idx1[nb * 32 + 256 + tid];
  }
  __syncthreads();
  float s = 0.f, q = 0.f;
  for (int ln = 0; ln < 16; ++ln) {
    float pv = Pp[(size_t)(nb + ln) * 64 + c];
    for (int e = grp; e < 32; e += 4) {
      int j = sidx[ln * 32 + e];
      float v = fmaxf(pv + Qn[(size_t)j * 64 + c], 0.f);
      s += v; q = fmaf(v, v, q);
    }
  }
  int slot = (blockIdx.x * 4 + grp) & 63;
  atomicAdd(&statsP[(size_t)slot * 1024 + c], s);
  atomicAdd(&statsP[(size_t)slot * 1024 + 512 + c], q);
}

// ---------------- conv2 fused edge reduce ----------------
// per node: mx/mn over relu(R_i + T_j) for 32 neighbors; global stats (slotted)
__global__ __launch_bounds__(128)
void mk_econv2(const float* __restrict__ R, const float* __restrict__ T,
               const int* __restrict__ st_i, float* __restrict__ mxp,
               float* __restrict__ mnp, float* __restrict__ statsP) {
  __shared__ int sidx[256];
  int tid = threadIdx.x;
  int nb = blockIdx.x * 8;
  sidx[tid] = st_i[nb * 32 + tid];
  sidx[tid + 128] = st_i[nb * 32 + 128 + tid];
  __syncthreads();
  float s = 0.f, q = 0.f;
  for (int ln = 0; ln < 8; ++ln) {
    int i = nb + ln;
    float rv = R[(size_t)i * 128 + tid];
    float mx = -3.4e38f, mn = 3.4e38f;
    for (int e = 0; e < 32; ++e) {
      int j = sidx[ln * 32 + e];
      float v = fmaxf(rv + T[(size_t)j * 128 + tid], 0.f);
      mx = fmaxf(mx, v); mn = fminf(mn, v);
      s += v; q = fmaf(v, v, q);
    }
    mxp[(size_t)i * 128 + tid] = mx;
    mnp[(size_t)i * 128 + tid] = mn;
  }
  int slot = blockIdx.x & 63;
  atomicAdd(&statsP[(size_t)slot * 1024 + tid], s);
  atomicAdd(&statsP[(size_t)slot * 1024 + 512 + tid], q);
}

// ---------------- BN finalize (slotted stats) ----------------
__global__ void mk_bnfinS(const float* __restrict__ sb, const float* __restrict__ g,
                          const float* __restrict__ beta, float* __restrict__ bno,
                          float Minv, int Cdim) {
  int c = blockIdx.x * 256 + threadIdx.x;
  if (c >= Cdim) return;
  float s = 0.f, q = 0.f;
  for (int sl = 0; sl < 64; ++sl) {
    s += sb[(size_t)sl * 1024 + c];
    q += sb[(size_t)sl * 1024 + 512 + c];
  }
  float mu = s * Minv;
  float var = q * Minv - mu * mu;
  float a = g[c] * rsqrtf(var + BN_EPS);
  bno[c] = a;
  bno[512 + c] = beta[c] - a * mu;
}

// ---------------- pooled-feature finalize ----------------
__global__ void mk_finx1(const float* __restrict__ mx, const float* __restrict__ mn,
                         const float* __restrict__ bn, float* __restrict__ x1,
                         short* __restrict__ x1h, short* __restrict__ x1l) {
  int g = blockIdx.x * 256 + threadIdx.x;
  if (g >= 8192 * 64) return;
  int c = g & 63;
  float a = bn[c], b = bn[512 + c];
  float v = (a > 0.f) ? fmaf(a, mx[g], b) : fmaf(a, mn[g], b);
  x1[g] = v;
  unsigned short h = f2bf(v);
  x1h[g] = (short)h;
  x1l[g] = (short)f2bf(v - bf2f(h));
}
__global__ void mk_finx2(const float* __restrict__ mx, const float* __restrict__ mn,
                         const float* __restrict__ bn, float* __restrict__ x2) {
  int g = blockIdx.x * 256 + threadIdx.x;
  if (g >= 8192 * 128) return;
  int c = g & 127;
  float a = bn[c], b = bn[512 + c];
  x2[g] = (a > 0.f) ? fmaf(a, mx[g], b) : fmaf(a, mn[g], b);
}

// ---------------- kNN selection ----------------
struct KCtl { unsigned B1, cum1, B2, cum2, acc, bnd; };

__device__ __forceinline__ void find_bin(const unsigned* hist, unsigned target,
                                         unsigned* outB, unsigned* outCum) {
  int lane = threadIdx.x;
  unsigned run = 0;
  for (int c = 0; c < KB / 64; ++c) {
    unsigned v = hist[c * 64 + lane];
    unsigned s = v;
#pragma unroll
    for (int off = 1; off < 64; off <<= 1) {
      unsigned t = __shfl_up(s, off, 64);
      if (lane >= off) s += t;
    }
    unsigned tot = __shfl(s, 63, 64);
    if (run + tot >= target) {
      unsigned long long mask = __ballot((run + s) >= target);
      int first = __ffsll((unsigned long long)mask) - 1;
      unsigned vf = __shfl(v, first, 64);
      unsigned sf = __shfl(s, first, 64);
      if (lane == 0) { *outB = (unsigned)(c * 64 + first); *outCum = run + sf - vf; }
      return;
    }
    run += tot;
  }
  if (lane == 0) { *outB = KB - 1; *outCum = run; }
}

__global__ __launch_bounds__(256)
void mk_knn1(const float* __restrict__ pos, const float* __restrict__ sq,
             int* __restrict__ idxout) {
  __shared__ unsigned hist[KB];
  __shared__ unsigned long long bbuf[MAXB2];
  __shared__ KCtl ctl;
  int q = blockIdx.x, tid = threadIdx.x;
  for (int b = tid; b < KB; b += 256) hist[b] = 0;
  if (tid == 0) { ctl.acc = 0; ctl.bnd = 0; }
  float qx = pos[q * 3], qy = pos[q * 3 + 1], qz = pos[q * 3 + 2], sqq = sq[q];
  unsigned key[32];
  __syncthreads();
#pragma unroll
  for (int c = 0; c < 32; ++c) {
    int j = c * 256 + tid;
    float d = sqq + sq[j] - 2.f * (qx * pos[j * 3] + qy * pos[j * 3 + 1] + qz * pos[j * 3 + 2]);
    unsigned k = (j == q) ? 0xFFFFFFFFu : ordf(d);
    key[c] = k;
    atomicAdd(&hist[k >> 21], 1u);
  }
  __syncthreads();
  if (tid < 64) find_bin(hist, 32u, &ctl.B1, &ctl.cum1);
  __syncthreads();
  unsigned B1 = ctl.B1, cum1 = ctl.cum1;
  int refine = hist[B1] > MAXB2;
  unsigned B2 = 0;
  if (refine) {
    __syncthreads();
    for (int b = tid; b < KB; b += 256) hist[b] = 0;
    __syncthreads();
#pragma unroll
    for (int c = 0; c < 32; ++c)
      if ((key[c] >> 21) == B1) atomicAdd(&hist[(key[c] >> 10) & 0x7FFu], 1u);
    __syncthreads();
    if (tid < 64) find_bin(hist, 32u - cum1, &ctl.B2, &ctl.cum2);
    __syncthreads();
    B2 = ctl.B2;
  }
#pragma unroll
  for (int c = 0; c < 32; ++c) {
    unsigned k = key[c];
    unsigned b = k >> 21;
    int j = c * 256 + tid;
    bool acc_e, bnd_e;
    if (!refine) { acc_e = b < B1; bnd_e = (b == B1); }
    else {
      unsigned l2 = (k >> 10) & 0x7FFu;
      acc_e = (b < B1) || (b == B1 && l2 < B2);
      bnd_e = (b == B1 && l2 == B2);
    }
    if (acc_e) { unsigned s = atomicAdd(&ctl.acc, 1u); idxout[q * 32 + s] = j; }
    else if (bnd_e) {
      unsigned s = atomicAdd(&ctl.bnd, 1u);
      if (s < MAXB2) bbuf[s] = (((unsigned long long)k) << 32) | (unsigned)j;
    }
  }
  __syncthreads();
  int acc = (int)ctl.acc, need = 32 - acc;
  int m = (int)ctl.bnd; if (m > MAXB2) m = MAXB2;
  for (int e = tid; e < m; e += 256) {
    unsigned long long me = bbuf[e];
    int rank = 0;
    for (int f = 0; f < m; ++f) rank += (bbuf[f] < me) ? 1 : 0;
    if (rank < need) idxout[q * 32 + acc + rank] = (int)(unsigned)(me & 0xFFFFFFFFu);
  }
}

__global__ __launch_bounds__(256)
void mk_knn2(const float* __restrict__ S, const float* __restrict__ sq,
             int c0, int first,
             unsigned* __restrict__ st_k, int* __restrict__ st_i) {
  __shared__ unsigned hist[KB];
  __shared__ unsigned long long bbuf[MAXB2];
  __shared__ KCtl ctl;
  int q = blockIdx.x, tid = threadIdx.x;
  for (int b = tid; b < KB; b += 256) hist[b] = 0;
  if (tid == 0) { ctl.acc = 0; ctl.bnd = 0; }
  float sqq = sq[q];
  unsigned key[8];
  unsigned ckey = 0xFFFFFFFFu; int cj = 0;
  int hascarry = (tid < 32) && !first;
  if (hascarry) { ckey = st_k[q * 32 + tid]; cj = st_i[q * 32 + tid]; }
  __syncthreads();
#pragma unroll
  for (int c = 0; c < 8; ++c) {
    int t = c * 256 + tid;
    int j = c0 + t;
    float d = sqq + sq[j] - 2.f * S[(size_t)q * 2048 + t];
    unsigned k = (j == q) ? 0xFFFFFFFFu : ordf(d);
    key[c] = k;
    atomicAdd(&hist[k >> 21], 1u);
  }
  if (hascarry) atomicAdd(&hist[ckey >> 21], 1u);
  __syncthreads();
  if (tid < 64) find_bin(hist, 32u, &ctl.B1, &ctl.cum1);
  __syncthreads();
  unsigned B1 = ctl.B1, cum1 = ctl.cum1;
  int refine = hist[B1] > MAXB2;
  unsigned B2 = 0;
  if (refine) {
    __syncthreads();
    for (int b = tid; b < KB; b += 256) hist[b] = 0;
    __syncthreads();
#pragma unroll
    for (int c = 0; c < 8; ++c)
      if ((key[c] >> 21) == B1) atomicAdd(&hist[(key[c] >> 10) & 0x7FFu], 1u);
    if (hascarry && (ckey >> 21) == B1) atomicAdd(&hist[(ckey >> 10) & 0x7FFu], 1u);
    __syncthreads();
    if (tid < 64) find_bin(hist, 32u - cum1, &ctl.B2, &ctl.cum2);
    __syncthreads();
    B2 = ctl.B2;
  }
  auto classify = [&](unsigned k, int j) {
    unsigned b = k >> 21;
    bool acc_e, bnd_e;
    if (!refine) { acc_e = b < B1; bnd_e = (b == B1); }
    else {
      unsigned l2 = (k >> 10) & 0x7FFu;
      acc_e = (b < B1) || (b == B1 && l2 < B2);
      bnd_e = (b == B1 && l2 == B2);
    }
    if (acc_e) {
      unsigned s = atomicAdd(&ctl.acc, 1u);
      st_k[q * 32 + s] = k; st_i[q * 32 + s] = j;
    } else if (bnd_e) {
      unsigned s = atomicAdd(&ctl.bnd, 1u);
      if (s < MAXB2) bbuf[s] = (((unsigned long long)k) << 32) | (unsigned)j;
    }
  };
#pragma unroll
  for (int c = 0; c < 8; ++c) classify(key[c], c0 + c * 256 + tid);
  if (hascarry) classify(ckey, cj);
  __syncthreads();
  int acc = (int)ctl.acc, need = 32 - acc;
  int m = (int)ctl.bnd; if (m > MAXB2) m = MAXB2;
  for (int e = tid; e < m; e += 256) {
    unsigned long long me = bbuf[e];
    int rank = 0;
    for (int f = 0; f < m; ++f) rank += (bbuf[f] < me) ? 1 : 0;
    if (rank < need) {
      st_k[q * 32 + acc + rank] = (unsigned)(me >> 32);
      st_i[q * 32 + acc + rank] = (int)(unsigned)(me & 0xFFFFFFFFu);
    }
  }
}

// ---------------- fp32 GEMM (small-K tag1) ----------------
#define GBM 64
#define GBN 64
#define GBK 16

__global__ __launch_bounds__(256)
void mk_gemm(const float* __restrict__ A, const float* __restrict__ W, int ldw,
             const float* __restrict__ bias, float* __restrict__ C, int ldc,
             int M, int N, int K, int flags) {
  __shared__ float As[GBK][GBM + 4];
  __shared__ float Ws[GBK][GBN];
  int tid = threadIdx.x;
  int r0 = blockIdx.x * GBM, n0 = blockIdx.y * GBN;
  int ty = tid >> 4, tx = tid & 15;
  float acc[4][4] = {};
  for (int kt = 0; kt < K; kt += GBK) {
#pragma unroll
    for (int it = 0; it < 4; ++it) {
      int l = it * 256 + tid;
      int r = l >> 4, kk = l & 15;
      int gr = r0 + r, gk = kt + kk;
      float v = 0.f;
      if (gk < K && gr < M) v = A[(size_t)gr * K + gk];
      As[kk][r] = v;
      int kw = l >> 6, nw = l & 63;
      int gkw = kt + kw;
      Ws[kw][nw] = (gkw < K && (n0 + nw) < N) ? W[(size_t)gkw * ldw + n0 + nw] : 0.f;
    }
    __syncthreads();
#pragma unroll
    for (int kk = 0; kk < GBK; ++kk) {
      float4 a4 = *(const float4*)&As[kk][ty * 4];
      float4 b4 = *(const float4*)&Ws[kk][tx * 4];
      float av[4] = {a4.x, a4.y, a4.z, a4.w};
      float bv[4] = {b4.x, b4.y, b4.z, b4.w};
#pragma unroll
      for (int i = 0; i < 4; ++i)
#pragma unroll
        for (int j = 0; j < 4; ++j)
          acc[i][j] = fmaf(av[i], bv[j], acc[i][j]);
    }
    __syncthreads();
  }
#pragma unroll
  for (int i = 0; i < 4; ++i) {
    int gr = r0 + ty * 4 + i;
    if (gr >= M) continue;
#pragma unroll
    for (int j = 0; j < 4; ++j) {
      int gc = n0 + tx * 4 + j;
      if (gc >= N) continue;
      float v = acc[i][j];
      if (bias) v += bias[gc];
      if (flags & 1) v += C[(size_t)gr * ldc + gc];
      if (flags & 2) v = fmaxf(v, 0.f);
      C[(size_t)gr * ldc + gc] = v;
    }
  }
}

// ---------------- small utility kernels ----------------
__global__ void mk_sqnorm(const float* __restrict__ x, float* __restrict__ sq, int Npts, int Cdim) {
  int i = blockIdx.x * blockDim.x + threadIdx.x;
  if (i >= Npts) return;
  float s = 0.f;
  for (int c = 0; c < Cdim; ++c) { float v = x[(size_t)i * Cdim + c]; s = fmaf(v, v, s); }
  sq[i] = s;
}

__global__ __launch_bounds__(256)
void mk_stats(const float* __restrict__ h, float* __restrict__ stats, int M, int Cdim, int RPB) {
  __shared__ float ssum[512], ssq[512];
  for (int c = threadIdx.x; c < Cdim; c += 256) { ssum[c] = 0.f; ssq[c] = 0.f; }
  __syncthreads();
  int G = Cdim >> 2;
  int c4 = (threadIdx.x % G) * 4;
  int rsub = threadIdx.x / G;
  int step = 256 / G;
  int r0 = blockIdx.x * RPB;
  int r1 = r0 + RPB; if (r1 > M) r1 = M;
  float s0 = 0, s1 = 0, s2 = 0, s3 = 0, q0 = 0, q1 = 0, q2 = 0, q3 = 0;
  for (int r = r0 + rsub; r < r1; r += step) {
    float4 v = *(const float4*)&h[(size_t)r * Cdim + c4];
    s0 += v.x; s1 += v.y; s2 += v.z; s3 += v.w;
    q0 = fmaf(v.x, v.x, q0); q1 = fmaf(v.y, v.y, q1);
    q2 = fmaf(v.z, v.z, q2); q3 = fmaf(v.w, v.w, q3);
  }
  atomicAdd(&ssum[c4 + 0], s0); atomicAdd(&ssum[c4 + 1], s1);
  atomicAdd(&ssum[c4 + 2], s2); atomicAdd(&ssum[c4 + 3], s3);
  atomicAdd(&ssq[c4 + 0], q0); atomicAdd(&ssq[c4 + 1], q1);
  atomicAdd(&ssq[c4 + 2], q2); atomicAdd(&ssq[c4 + 3], q3);
  __syncthreads();
  for (int c = threadIdx.x; c < Cdim; c += 256) {
    atomicAdd(&stats[c], ssum[c]);
    atomicAdd(&stats[512 + c], ssq[c]);
  }
}

__global__ void mk_bnfin(const float* __restrict__ stats, const float* __restrict__ g,
                         const float* __restrict__ beta, float* __restrict__ bn,
                         float Minv, int Cdim) {
  int c = blockIdx.x * blockDim.x + threadIdx.x;
  if (c >= Cdim) return;
  float mu = stats[c] * Minv;
  float var = stats[512 + c] * Minv - mu * mu;
  float a = g[c] * rsqrtf(var + BN_EPS);
  bn[c] = a;
  bn[512 + c] = beta[c] - a * mu;
}

// ---------------- CSR build + props ----------------
__global__ void mk_count(const int* __restrict__ col, int* __restrict__ cnt, int E) {
  int e = blockIdx.x * 256 + threadIdx.x;
  if (e < E) atomicAdd(&cnt[col[e]], 1);
}
__global__ void mk_dinv2(const int* __restrict__ cnt, float* __restrict__ dinvf) {
  int i = blockIdx.x * 256 + threadIdx.x;
  if (i >= 8192) return;
  int d = cnt[i];
  dinvf[i] = (d > 0) ? rsqrtf((float)(d < 1 ? 1 : d)) : 0.f;
}
__global__ __launch_bounds__(1024)
void mk_scan(const int* __restrict__ cnt, int* __restrict__ offp) {
  __shared__ int wsum[16];
  __shared__ int wexc[16];
  int t = threadIdx.x, lane = t & 63, w = t >> 6;
  int v[8]; int s = 0;
  int base = t * 8;
#pragma unroll
  for (int k = 0; k < 8; ++k) { v[k] = s; s += cnt[base + k]; }
  int sc = s;
#pragma unroll
  for (int off2 = 1; off2 < 64; off2 <<= 1) {
    int n = __shfl_up(sc, off2, 64);
    if (lane >= off2) sc += n;
  }
  if (lane == 63) wsum[w] = sc;
  __syncthreads();
  if (w == 0) {
    int x = (lane < 16) ? wsum[lane] : 0;
    int scx = x;
#pragma unroll
    for (int off2 = 1; off2 < 16; off2 <<= 1) {
      int n = __shfl_up(scx, off2, 64);
      if (lane >= off2) scx += n;
    }
    if (lane < 16) wexc[lane] = scx - x;
  }
  __syncthreads();
  int texc = wexc[w] + (sc - s);
#pragma unroll
  for (int k = 0; k < 8; ++k) offp[base + k] = texc + v[k];
  if (t == 1023) offp[8192] = texc + s;
}
__global__ void mk_copyoff(const int* __restrict__ offp, int* __restrict__ cur) {
  int i = blockIdx.x * 256 + threadIdx.x;
  if (i < 8192) cur[i] = offp[i];
}
__global__ void mk_fill(const int* __restrict__ row, const int* __restrict__ col,
                        const float* __restrict__ dinvf, int* __restrict__ cur,
                        int* __restrict__ crow, float* __restrict__ cw, int E) {
  int e = blockIdx.x * 256 + threadIdx.x;
  if (e >= E) return;
  int c = col[e], r = row[e];
  int s = atomicAdd(&cur[c], 1);
  crow[s] = r;
  cw[s] = dinvf[r] * dinvf[c];
}
__global__ void mk_prop64(const float* __restrict__ h, const int* __restrict__ offp,
                          const int* __restrict__ crow, const float* __restrict__ cw,
                          float* __restrict__ out) {
  int gid = blockIdx.x * 256 + threadIdx.x;
  if (gid >= 8192 * 16) return;
  int col = gid >> 4, c4 = (gid & 15) * 4;
  int s0 = offp[col], s1 = offp[col + 1];
  float a0 = 0, a1 = 0, a2 = 0, a3 = 0;
  for (int s = s0; s < s1; ++s) {
    int r = crow[s]; float w = cw[s];
    float4 v = *(const float4*)&h[(size_t)r * 64 + c4];
    a0 = fmaf(w, v.x, a0); a1 = fmaf(w, v.y, a1);
    a2 = fmaf(w, v.z, a2); a3 = fmaf(w, v.w, a3);
  }
  float4 o = {a0, a1, a2, a3};
  *(float4*)&out[(size_t)col * 64 + c4] = o;
}
__global__ void mk_prop4(const float* __restrict__ h, const int* __restrict__ offp,
                         const int* __restrict__ crow, const float* __restrict__ cw,
                         float* __restrict__ out) {
  int col = blockIdx.x * 256 + threadIdx.x;
  if (col >= 8192) return;
  int s0 = offp[col], s1 = offp[col + 1];
  float a0 = 0, a1 = 0, a2 = 0, a3 = 0;
  for (int s = s0; s < s1; ++s) {
    int r = crow[s]; float w = cw[s];
    float4 v = *(const float4*)&h[(size_t)r * 4];
    a0 = fmaf(w, v.x, a0); a1 = fmaf(w, v.y, a1);
    a2 = fmaf(w, v.z, a2); a3 = fmaf(w, v.w, a3);
  }
  float4 o = {a0, a1, a2, a3};
  *(float4*)&out[(size_t)col * 4] = o;
}

__global__ __launch_bounds__(256)
void mk_gemv_out(const float* __restrict__ h, const float* __restrict__ bn,
                 const float* __restrict__ w, const float* __restrict__ b,
                 float* __restrict__ out, int Npts) {
  int row = blockIdx.x * 4 + (threadIdx.x >> 6);
  int lane = threadIdx.x & 63;
  if (row >= Npts) return;
  int c = lane * 4;
  float4 v = *(const float4*)&h[(size_t)row * 256 + c];
  float s = (bn[c] * v.x + bn[512 + c]) * w[c]
          + (bn[c + 1] * v.y + bn[512 + c + 1]) * w[c + 1]
          + (bn[c + 2] * v.z + bn[512 + c + 2]) * w[c + 2]
          + (bn[c + 3] * v.w + bn[512 + c + 3]) * w[c + 3];
#pragma unroll
  for (int off = 32; off; off >>= 1) s += __shfl_xor(s, off, 64);
  if (lane == 0) out[row] = s + b[0];
}

// ---------------- host ----------------
extern "C" void kernel_launch(void* const* d_in, const int* in_sizes, int n_in,
                              void* d_out, int out_size, void* d_ws, size_t ws_size,
                              hipStream_t stream) {
  const int N = 8192;
  const int NE = N * 32;
  const float* pos = (const float*)d_in[0];
  const float* xin = (const float*)d_in[1];
  const int* ei = (const int*)d_in[2];
  const int E = in_sizes[2] / 2;
  const int* erow = ei;
  const int* ecol = ei + E;
  const float* mlp1_W1  = (const float*)d_in[3];
  const float* mlp1_W23 = (const float*)d_in[4];
  const float* mlp1_b   = (const float*)d_in[5];
  const float* mlp1_g   = (const float*)d_in[6];
  const float* mlp1_be  = (const float*)d_in[7];
  const float* mlp2_W   = (const float*)d_in[8];
  const float* mlp2_b   = (const float*)d_in[9];
  const float* mlp2_g   = (const float*)d_in[10];
  const float* mlp2_be  = (const float*)d_in[11];
  const float* lin1_W   = (const float*)d_in[12];
  const float* lin1_b   = (const float*)d_in[13];
  const float* lin1_g   = (const float*)d_in[14];
  const float* lin1_be  = (const float*)d_in[15];
  const float* tag1_W   = (const float*)d_in[16];
  const float* tag1_b   = (const float*)d_in[17];
  const float* tag2_W   = (const float*)d_in[18];
  const float* tag2_b   = (const float*)d_in[19];
  const float* lin2_W   = (const float*)d_in[20];
  const float* lin2_b   = (const float*)d_in[21];
  const float* lin2_g   = (const float*)d_in[22];
  const float* lin2_be  = (const float*)d_in[23];
  const float* mix1_W   = (const float*)d_in[24];
  const float* mix1_b   = (const float*)d_in[25];
  const float* mix1_g   = (const float*)d_in[26];
  const float* mix1_be  = (const float*)d_in[27];
  const float* mix2_W   = (const float*)d_in[28];
  const float* mix2_b   = (const float*)d_in[29];
  const float* mix2_g   = (const float*)d_in[30];
  const float* mix2_be  = (const float*)d_in[31];
  const float* outW     = (const float*)d_in[32];
  const float* outB     = (const float*)d_in[33];

  char* base = (char*)d_ws;
  size_t off = 0;
  auto alloc = [&](size_t b) -> void* {
    void* p = base + off;
    off += (b + 255) & ~(size_t)255;
    return p;
  };
  float* BIG = (float*)alloc(134217728ull);   // 128 MB phase-shared
  float* h2 = BIG;                            // [262144][64] 64 MB (conv1 L2 out)
  float* Sb = BIG;                            // knn2 chunk 64 MB (after L3)
  float* out_dg = BIG;                        // head phase
  float* out_g  = BIG + 4194304;
  float* mh1    = BIG + 8388608;
  float* mh2    = BIG + 12582912;
  int*   idx1 = (int*)alloc((size_t)NE * 4);
  unsigned* st_k = (unsigned*)alloc((size_t)NE * 4);
  int*   st_i = (int*)alloc((size_t)NE * 4);
  float* x1  = (float*)alloc((size_t)N * 64 * 4);
  float* x2  = (float*)alloc((size_t)N * 128 * 4);
  float* g1  = (float*)alloc((size_t)N * 64 * 4);
  float* g2  = (float*)alloc((size_t)N * 128 * 4);
  float* sqp = (float*)alloc((size_t)N * 4);
  float* sqx = (float*)alloc((size_t)N * 4);
  float* Pp  = (float*)alloc((size_t)N * 64 * 4);
  float* Qn  = (float*)alloc((size_t)N * 64 * 4);
  float* Rb  = (float*)alloc((size_t)N * 128 * 4);
  float* Tb  = (float*)alloc((size_t)N * 128 * 4);
  float* mx1 = (float*)alloc((size_t)N * 64 * 4);
  float* mn1 = (float*)alloc((size_t)N * 64 * 4);
  float* mx2 = (float*)alloc((size_t)N * 128 * 4);
  float* mn2 = (float*)alloc((size_t)N * 128 * 4);
  float* tpa = (float*)alloc((size_t)N * 64 * 4);
  float* tpb = (float*)alloc((size_t)N * 64 * 4);
  float* tp4a = (float*)alloc((size_t)N * 4 * 4);
  float* tp4b = (float*)alloc((size_t)N * 4 * 4);
  float* dinvf = (float*)alloc((size_t)N * 4);
  int* cnt     = (int*)alloc((size_t)N * 4);
  int* csr_off = (int*)alloc((size_t)(N + 1) * 4);
  int* cursor  = (int*)alloc((size_t)N * 4);
  int* csr_row = (int*)alloc((size_t)E * 4);
  float* csr_w = (float*)alloc((size_t)E * 4);
  float* slotAll = (float*)alloc(4 * 64 * 1024 * 4);  // 1 MB slotted stats
  auto slot = [&](int i) { return slotAll + (size_t)i * 64 * 1024; };
  float* stats8 = (float*)alloc(8 * 1024 * 4);
  float* bnb = (float*)alloc(8 * 1024 * 4);
  auto bnp = [&](int i) { return bnb + (size_t)i * 1024; };
  auto stp = [&](int i) { return stats8 + (size_t)i * 1024; };
  auto salloc = [&](size_t n) { return (short*)alloc(n * 2); };
  short* w23a_h = salloc(4096);   short* w23a_l = salloc(4096);
  short* w23b_h = salloc(4096);   short* w23b_l = salloc(4096);
  short* wd2_h  = salloc(8192);   short* wd2_l  = salloc(8192);
  short* wv2_h  = salloc(8192);   short* wv2_l  = salloc(8192);
  short* wl1_h  = salloc(98304);  short* wl1_l  = salloc(98304);
  short* wt2_h  = salloc(32768);  short* wt2_l  = salloc(32768);
  short* wl2_h  = salloc(98304);  short* wl2_l  = salloc(98304);
  short* wx1_h  = salloc(524288); short* wx1_l  = salloc(524288);
  short* wx2_h  = salloc(131072); short* wx2_l  = salloc(131072);
  short* x1h    = salloc(524288); short* x1l    = salloc(524288);

  auto gemmF = [&](const float* A, const short* A8h, const short* A8l,
                   const float* src, const int* gidx, int srcC, const float* bnA,
                   const short* Wh_, const short* Wl_, int ldk, int koff,
                   const float* bias, float* Cp, int ldc,
                   int M, int Nn, int Kk, int flags,
                   float* stP = nullptr, float* mxP = nullptr, float* mnP = nullptr) {
    dim3 g(M / 64, Nn / 64);
    mk_gemm_mfma<<<g, 256, 0, stream>>>(A, A8h, A8l, src, gidx, srcC, bnA,
                                        Wh_, Wl_, ldk, koff, bias, Cp, ldc,
                                        M, Nn, Kk, flags, stP, mxP, mnP);
  };
  auto wcvt = [&](const float* W, short* Wh_, short* Wl_, int Kk, int Nn) {
    mk_wcvt<<<(Kk * Nn + 255) / 256, 256, 0, stream>>>(W, Wh_, Wl_, Kk, Nn);
  };
  auto statsbn = [&](const float* h, int M, int C, const float* gg, const float* bb,
                     float* st, float* bno) {
    mk_stats<<<128, 256, 0, stream>>>(h, st, M, C, (M + 127) / 128);
    mk_bnfin<<<(C + 255) / 256, 256, 0, stream>>>(st, gg, bb, bno, 1.f / M, C);
  };

  // ---- init + weight conversion ----
  hipMemsetAsync(slotAll, 0, 4 * 64 * 1024 * 4, stream);
  hipMemsetAsync(stats8, 0, 8 * 1024 * 4, stream);
  hipMemsetAsync(cnt, 0, (size_t)N * 4, stream);
  wcvt(mlp1_W23,        w23a_h, w23a_l, 64, 64);
  wcvt(mlp1_W23 + 4096, w23b_h, w23b_l, 64, 64);
  mk_wcvt2<<<(64 * 128 + 255) / 256, 256, 0, stream>>>(mlp2_W, wd2_h, wd2_l, wv2_h, wv2_l);
  wcvt(lin1_W, wl1_h, wl1_l, 192, 512);
  for (int hop = 0; hop < 4; ++hop)
    wcvt(tag2_W + hop * 8192, wt2_h + hop * 8192, wt2_l + hop * 8192, 64, 128);
  wcvt(lin2_W, wl2_h, wl2_l, 192, 512);
  wcvt(mix1_W, wx1_h, wx1_l, 1024, 512);
  wcvt(mix2_W, wx2_h, wx2_l, 512, 256);

  // ---- kNN-1 on pos ----
  mk_sqnorm<<<32, 256, 0, stream>>>(pos, sqp, N, 3);
  mk_knn1<<<N, 256, 0, stream>>>(pos, sqp, idx1);

  // ---- conv1: node tables + streaming stats of h1 ----
  mk_conv1nodes<<<(N * 64 + 255) / 256, 256, 0, stream>>>(pos, mlp1_W1, mlp1_b, Pp, Qn);
  mk_stats1<<<512, 256, 0, stream>>>(Pp, Qn, idx1, slot(0));
  mk_bnfinS<<<1, 256, 0, stream>>>(slot(0), mlp1_g, mlp1_be, bnp(0), 1.f / NE, 64);
  // L2: A computed on-the-fly from (Pp,Qn,idx1), stats fused
  gemmF(Pp, nullptr, nullptr, Qn, idx1, 64, bnp(0),
        w23a_h, w23a_l, 64, 0, mlp1_b + 64, h2, 64, NE, 64, 64, 2 | 8 | 32, slot(1));
  mk_bnfinS<<<1, 256, 0, stream>>>(slot(1), mlp1_g + 64, mlp1_be + 64, bnp(1), 1.f / NE, 64);
  // L3: stats + per-node max/min fused, h3 never written
  gemmF(h2, nullptr, nullptr, nullptr, nullptr, 0, bnp(1),
        w23b_h, w23b_l, 64, 0, mlp1_b + 128, nullptr, 64, NE, 64, 64, 2 | 8 | 16,
        slot(2), mx1, mn1);
  mk_bnfinS<<<1, 256, 0, stream>>>(slot(2), mlp1_g + 128, mlp1_be + 128, bnp(2), 1.f / NE, 64);
  mk_finx1<<<(N * 64 + 255) / 256, 256, 0, stream>>>(mx1, mn1, bnp(2), x1, x1h, x1l);

  // ---- kNN-2 on x1 (chunked S = x1 @ x1^T) ----
  mk_sqnorm<<<32, 256, 0, stream>>>(x1, sqx, N, 64);
  for (int c = 0; c < 4; ++c) {
    gemmF(nullptr, x1h, x1l, nullptr, nullptr, 0, nullptr,
          x1h + (size_t)c * 2048 * 64, x1l + (size_t)c * 2048 * 64, 64, 0,
          nullptr, Sb, 2048, N, 2048, 64, 0);
    mk_knn2<<<N, 256, 0, stream>>>(Sb, sqx, c * 2048, c == 0 ? 1 : 0, st_k, st_i);
  }

  // ---- conv2: node GEMMs + fused edge reduce ----
  gemmF(nullptr, x1h, x1l, nullptr, nullptr, 0, nullptr,
        wd2_h, wd2_l, 64, 0, mlp2_b, Rb, 128, N, 128, 64, 0);
  gemmF(nullptr, x1h, x1l, nullptr, nullptr, 0, nullptr,
        wv2_h, wv2_l, 64, 0, nullptr, Tb, 128, N, 128, 64, 0);
  mk_econv2<<<N / 8, 128, 0, stream>>>(Rb, Tb, st_i, mx2, mn2, slot(3));
  mk_bnfinS<<<1, 256, 0, stream>>>(slot(3), mlp2_g, mlp2_be, bnp(3), 1.f / NE, 128);
  mk_finx2<<<(N * 128 + 255) / 256, 256, 0, stream>>>(mx2, mn2, bnp(3), x2);

  // ---- lin1: [x1,x2] -> 512 ----
  gemmF(nullptr, x1h, x1l, nullptr, nullptr, 0, nullptr,
        wl1_h, wl1_l, 192, 0, nullptr, out_dg, 512, N, 512, 64, 0);
  gemmF(x2, nullptr, nullptr, nullptr, nullptr, 0, nullptr,
        wl1_h, wl1_l, 192, 64, lin1_b, out_dg, 512, N, 512, 128, 1 | 2);
  statsbn(out_dg, N, 512, lin1_g, lin1_be, stp(4), bnp(4));

  // ---- TAG branch: CSR build ----
  mk_count<<<(E + 255) / 256, 256, 0, stream>>>(ecol, cnt, E);
  mk_dinv2<<<32, 256, 0, stream>>>(cnt, dinvf);
  mk_scan<<<1, 1024, 0, stream>>>(cnt, csr_off);
  mk_copyoff<<<32, 256, 0, stream>>>(csr_off, cursor);
  mk_fill<<<(E + 255) / 256, 256, 0, stream>>>(erow, ecol, dinvf, cursor, csr_row, csr_w, E);
  // tag1 (C=4 -> 64)
  mk_gemm<<<dim3(128, 1), 256, 0, stream>>>(xin, tag1_W, 64, tag1_b, g1, 64, N, 64, 4, 0);
  mk_prop4<<<32, 256, 0, stream>>>(xin, csr_off, csr_row, csr_w, tp4a);
  mk_gemm<<<dim3(128, 1), 256, 0, stream>>>(tp4a, tag1_W + 256, 64, nullptr, g1, 64, N, 64, 4, 1);
  mk_prop4<<<32, 256, 0, stream>>>(tp4a, csr_off, csr_row, csr_w, tp4b);
  mk_gemm<<<dim3(128, 1), 256, 0, stream>>>(tp4b, tag1_W + 512, 64, nullptr, g1, 64, N, 64, 4, 1);
  mk_prop4<<<32, 256, 0, stream>>>(tp4b, csr_off, csr_row, csr_w, tp4a);
  mk_gemm<<<dim3(128, 1), 256, 0, stream>>>(tp4a, tag1_W + 768, 64, nullptr, g1, 64, N, 64, 4, 1 | 2);
  // tag2 (64 -> 128)
  gemmF(g1, nullptr, nullptr, nullptr, nullptr, 0, nullptr,
        wt2_h, wt2_l, 64, 0, tag2_b, g2, 128, N, 128, 64, 0);
  mk_prop64<<<512, 256, 0, stream>>>(g1, csr_off, csr_row, csr_w, tpa);
  gemmF(tpa, nullptr, nullptr, nullptr, nullptr, 0, nullptr,
        wt2_h + 8192, wt2_l + 8192, 64, 0, nullptr, g2, 128, N, 128, 64, 1);
  mk_prop64<<<512, 256, 0, stream>>>(tpa, csr_off, csr_row, csr_w, tpb);
  gemmF(tpb, nullptr, nullptr, nullptr, nullptr, 0, nullptr,
        wt2_h + 16384, wt2_l + 16384, 64, 0, nullptr, g2, 128, N, 128, 64, 1);
  mk_prop64<<<512, 256, 0, stream>>>(tpb, csr_off, csr_row, csr_w, tpa);
  gemmF(tpa, nullptr, nullptr, nullptr, nullptr, 0, nullptr,
        wt2_h + 24576, wt2_l + 24576, 64, 0, nullptr, g2, 128, N, 128, 64, 1 | 2);
  // lin2
  gemmF(g1, nullptr, nullptr, nullptr, nullptr, 0, nullptr,
        wl2_h, wl2_l, 192, 0, nullptr, out_g, 512, N, 512, 64, 0);
  gemmF(g2, nullptr, nullptr, nullptr, nullptr, 0, nullptr,
        wl2_h, wl2_l, 192, 64, lin2_b, out_g, 512, N, 512, 128, 1 | 2);
  statsbn(out_g, N, 512, lin2_g, lin2_be, stp(5), bnp(5));

  // ---- mix head ----
  gemmF(out_dg, nullptr, nullptr, nullptr, nullptr, 0, bnp(4),
        wx1_h, wx1_l, 1024, 0, nullptr, mh1, 512, N, 512, 512, 0);
  gemmF(out_g, nullptr, nullptr, nullptr, nullptr, 0, bnp(5),
        wx1_h, wx1_l, 1024, 512, mix1_b, mh1, 512, N, 512, 512, 1 | 2);
  statsbn(mh1, N, 512, mix1_g, mix1_be, stp(6), bnp(6));
  gemmF(mh1, nullptr, nullptr, nullptr, nullptr, 0, bnp(6),
        wx2_h, wx2_l, 512, 0, mix2_b, mh2, 256, N, 256, 512, 2);
  statsbn(mh2, N, 256, mix2_g, mix2_be, stp(7), bnp(7));
  mk_gemv_out<<<N / 4, 256, 0, stream>>>(mh2, bnp(7), outW, outB, (float*)d_out, N);
}